// Round 15
// baseline (926.790 us; speedup 1.0000x reference)
//
#include <hip/hip_runtime.h>
#include <hip/hip_bf16.h>
#include <stdint.h>

#define B_   32
#define K_   64
#define E_   512
#define H_   512
#define M_   512
#define T_   20
#define V_   32000
#define KIN  2048   // 2H + E + M
#define NBLK 32     // chain blocks / j-groups
#define NCONV 224   // conv helper blocks in k_step

typedef __bf16 bf16x8 __attribute__((ext_vector_type(8)));
typedef float  f32x4  __attribute__((ext_vector_type(4)));

__device__ inline unsigned short f2bf_rne(float f) {
  union { float f; unsigned u; } v; v.f = f;
  unsigned r = v.u + 0x7FFFu + ((v.u >> 16) & 1u);
  return (unsigned short)(r >> 16);
}
__device__ inline float bf2f(unsigned short s) {
  union { unsigned u; float f; } v; v.u = ((unsigned)s) << 16;
  return v.f;
}
__device__ inline float sigm(float x) { return 1.f / (1.f + expf(-x)); }
__device__ inline unsigned ordf(float f) {
  unsigned u = __float_as_uint(f);
  return (u & 0x80000000u) ? ~u : (u | 0x80000000u);
}
__device__ __forceinline__ void gload16(const void* g, void* l) {
  __builtin_amdgcn_global_load_lds(
      (const __attribute__((address_space(1))) void*)g,
      (__attribute__((address_space(3))) void*)l, 16, 0, 0);
}

// j-group mapping: block blk owns jj in [0,64): global j = (jj>>4)*512 + blk*16 + (jj&15)

// ---- prep: weight splits, enc/emb bf16, F emb cols, bias, zeros ----------
__global__ void k_prep(const float* __restrict__ W_ih, const float* __restrict__ W_hh,
                       const float* __restrict__ b_ih, const float* __restrict__ b_hh,
                       const float* __restrict__ enc, const float* __restrict__ embt,
                       const int* __restrict__ captions,
                       unsigned short* __restrict__ wih_hi, unsigned short* __restrict__ wih_lo,
                       unsigned short* __restrict__ whh_hi, unsigned short* __restrict__ whh_lo,
                       unsigned short* __restrict__ enc_bf, unsigned short* __restrict__ emb_bf,
                       float* __restrict__ bias_arr, float* __restrict__ score_part,
                       unsigned long long* __restrict__ argkey,
                       unsigned short* __restrict__ Fall) {
  int tid0 = blockIdx.x * 256 + threadIdx.x;
  int NT = gridDim.x * 256;
  for (int i = tid0; i < 2048 * 1024; i += NT) {            // W_ih hi/lo
    float f = W_ih[i];
    unsigned short h = f2bf_rne(f);
    wih_hi[i] = h; wih_lo[i] = f2bf_rne(f - bf2f(h));
  }
  for (int i = tid0; i < NBLK * 64 * 512; i += NT) {        // W_hh rearranged [blk][jj][512]
    int e = i & 511, jj = (i >> 9) & 63, blk = i >> 15;
    int jg = (jj >> 4) * 512 + blk * 16 + (jj & 15);
    float f = W_hh[jg * 512 + e];
    unsigned short h = f2bf_rne(f);
    whh_hi[i] = h; whh_lo[i] = f2bf_rne(f - bf2f(h));
  }
  for (int i = tid0; i < 2048 * 512; i += NT) enc_bf[i] = f2bf_rne(enc[i]);
  for (int i = tid0; i < 640 * 512; i += NT) {              // emb rows + F emb cols (tf=1)
    int n = i >> 9, m = i & 511;
    int t = n >> 5, b = n & 31;
    int tok = captions[b * T_ + (t > 0 ? t - 1 : 0)];
    unsigned short ev = f2bf_rne(embt[(size_t)tok * 512 + m]);
    emb_bf[i] = ev;
    Fall[(size_t)n * KIN + 1536 + m] = ev;
  }
  for (int i = tid0; i < 2048; i += NT) {                   // bias [blk][jj]
    int blk = i >> 6, jj = i & 63;
    int jg = (jj >> 4) * 512 + blk * 16 + (jj & 15);
    bias_arr[i] = b_ih[jg] + b_hh[jg];
  }
  for (int i = tid0; i < (T_ + 1) * 1024; i += NT) score_part[i] = 0.f;
  for (int i = tid0; i < 32; i += NT) argkey[i] = 0ull;
}

// ---- init: h0=c0=enc[:,-1,:], F[0] h/c bf16, enc_score, score_part[0] ----
__global__ void k_init(const float* __restrict__ enc, const float* __restrict__ Wa,
                       float* __restrict__ hb, float* __restrict__ cb,
                       unsigned short* __restrict__ Fall,
                       float* __restrict__ enc_score, float* __restrict__ score_part) {
  int idx = blockIdx.x * 256 + threadIdx.x;   // 64 blocks
  int b = idx >> 9, i = idx & 511;
  float v = enc[(size_t)b * K_ * E_ + (size_t)(K_ - 1) * E_ + i];
  hb[b * H_ + i] = v;
  cb[b * H_ + i] = v;
  unsigned short bv = f2bf_rne(v);
  Fall[b * KIN + i] = bv;
  Fall[b * KIN + H_ + i] = bv;
  if (idx < B_ * K_) {
    int bb = idx >> 6, k = idx & 63;
    const float4* e4  = (const float4*)(enc + ((size_t)bb * K_ + k) * E_);
    const float4* wa4 = (const float4*)(Wa + 2 * H_);
    float acc = 0.f;
    #pragma unroll 4
    for (int q = 0; q < E_ / 4; ++q) {
      float4 a = e4[q], w = wa4[q];
      acc += a.x * w.x + a.y * w.y + a.z * w.z + a.w * w.w;
    }
    enc_score[idx] = acc;
  }
  if (idx < 2048) {     // score_part[0][0][b] = dot([h0,c0], Wa[:1024]), h0=c0
    int bb = idx >> 6, l = idx & 63;
    float s = 0.f;
    #pragma unroll
    for (int q = 0; q < 8; ++q) {
      int ii = l * 8 + q;
      float hv = enc[(size_t)bb * K_ * E_ + (size_t)(K_ - 1) * E_ + ii];
      s += hv * (Wa[ii] + Wa[512 + ii]);
    }
    for (int o = 32; o; o >>= 1) s += __shfl_down(s, o);
    if (l == 0) score_part[bb] = s;
  }
}

// ---- precompute G = (W_ih hi/lo) @ B^T : out[blk][n][jj] fp32 ------------
__global__ __launch_bounds__(256) void k_gpre(
    const unsigned short* __restrict__ whi, const unsigned short* __restrict__ wlo,
    int koff, const unsigned short* __restrict__ Bm,
    float* __restrict__ outp, int N) {
  int blk = blockIdx.x, nt = blockIdx.y;
  int tid = threadIdx.x;
  int l = tid & 63, w = tid >> 6, lv = l & 15, lg = l >> 4;
  const int n0 = nt * 128 + w * 32;

  f32x4 acc[4][2];
  #pragma unroll
  for (int jf = 0; jf < 4; ++jf)
    #pragma unroll
    for (int nf = 0; nf < 2; ++nf) acc[jf][nf] = (f32x4){0.f, 0.f, 0.f, 0.f};

  #pragma unroll 4
  for (int kk = 0; kk < 16; ++kk) {
    bf16x8 bfr[2];
    #pragma unroll
    for (int nf = 0; nf < 2; ++nf)
      bfr[nf] = *(const bf16x8*)(Bm + (size_t)(n0 + nf * 16 + lv) * 512 + kk * 32 + lg * 8);
    #pragma unroll
    for (int jf = 0; jf < 4; ++jf) {
      int jg = jf * 512 + blk * 16 + lv;
      bf16x8 ahi = *(const bf16x8*)(whi + (size_t)jg * 1024 + koff + kk * 32 + lg * 8);
      bf16x8 alo = *(const bf16x8*)(wlo + (size_t)jg * 1024 + koff + kk * 32 + lg * 8);
      #pragma unroll
      for (int nf = 0; nf < 2; ++nf) {
        acc[jf][nf] = __builtin_amdgcn_mfma_f32_16x16x32_bf16(ahi, bfr[nf], acc[jf][nf], 0, 0, 0);
        acc[jf][nf] = __builtin_amdgcn_mfma_f32_16x16x32_bf16(alo, bfr[nf], acc[jf][nf], 0, 0, 0);
      }
    }
  }
  #pragma unroll
  for (int jf = 0; jf < 4; ++jf)
    #pragma unroll
    for (int nf = 0; nf < 2; ++nf)
      #pragma unroll
      for (int jr = 0; jr < 4; ++jr) {
        int n = n0 + nf * 16 + lv;
        int jj = jf * 16 + 4 * lg + jr;
        outp[((size_t)blk * N + n) * 64 + jj] = acc[jf][nf][jr];
      }
}

// ---- per step: blocks 0-31 chain; blocks 32-255 convert Wl slice t -------
__global__ __launch_bounds__(512) void k_step(
    const float* __restrict__ enc, const float* __restrict__ embt,
    const float* __restrict__ Wa, const float* __restrict__ ba,
    const float* __restrict__ W_ih, const float* __restrict__ W_hh,
    const float* __restrict__ b_ih, const float* __restrict__ b_hh,
    const float* __restrict__ Wl, const float* __restrict__ bl,
    const int* __restrict__ captions, const int* __restrict__ tf_flag,
    const float* __restrict__ Genc, const float* __restrict__ Gemb,
    const unsigned short* __restrict__ whh_hi, const unsigned short* __restrict__ whh_lo,
    const float* __restrict__ bias_arr, const float* __restrict__ enc_score,
    float* __restrict__ score_part, unsigned short* __restrict__ Fall,
    float* __restrict__ hb, float* __restrict__ cb,
    unsigned long long* __restrict__ argkey, unsigned short* __restrict__ wl_bf,
    int t) {
  const int blk = blockIdx.x;
  const int tid = threadIdx.x;

  if (blk >= NBLK) {
    // ---- convert Wl slice t (1/20 of the matrix), k_prep's verbatim loop -
    const int NC = V_ * KIN / 4;              // 16,384,000 f32x4's
    const int per = (NC + T_ - 1) / T_;       // 819,200
    int lo = t * per;
    int hi = lo + per; if (hi > NC) hi = NC;
    for (int i = lo + (blk - NBLK) * 512 + tid; i < hi; i += NCONV * 512) {
      f32x4 v = __builtin_nontemporal_load((const f32x4*)Wl + i);
      ushort4 o;
      o.x = f2bf_rne(v.x); o.y = f2bf_rne(v.y); o.z = f2bf_rne(v.z); o.w = f2bf_rne(v.w);
      ((ushort4*)wl_bf)[i] = o;
    }
    return;
  }

  __shared__ float attn_s[B_ * K_];
  __shared__ float gsA[64 * 33];
  __shared__ float gsH[2][64][32];
  __shared__ float scC[512];
  __shared__ float score_t_[32];
  __shared__ int   token_sp;
  __shared__ float xls[KIN];
  __shared__ float gls[2048];
  __shared__ unsigned long long bred[512];
  const float* cbc = cb + (t & 1) * B_ * H_;
  float* cbn = cb + ((t + 1) & 1) * B_ * H_;

  if (tf_flag[0]) {
    // phase 0: assemble scores (deterministic per-slot partials)
    if (tid < 32) {
      float s = 0.f;
      #pragma unroll 8
      for (int p = 0; p < 32; ++p) s += score_part[t * 1024 + p * 32 + tid];
      score_t_[tid] = s;
    }
    __syncthreads();
    // phase 1: softmax (8 waves x 4 batches; lanes = k)
    {
      int w = tid >> 6, l = tid & 63;
      float ba0 = ba[0];
      #pragma unroll
      for (int bb = 0; bb < 4; ++bb) {
        int b = w * 4 + bb;
        float s = tanhf(score_t_[b] + enc_score[b * 64 + l] + ba0);
        float m = s;
        for (int o = 32; o; o >>= 1) m = fmaxf(m, __shfl_xor(m, o));
        float e = expf(s - m);
        float sum = e;
        for (int o = 32; o; o >>= 1) sum += __shfl_xor(sum, o);
        attn_s[b * 64 + l] = e / sum;
      }
    }
    __syncthreads();
    // phase 2: gsA[jj][b] = sum_k attn*Genc + Gemb + bias (one quad/thread)
    {
      const f32x4* G4 = (const f32x4*)Genc;
      const f32x4* E4 = (const f32x4*)Gemb;
      const f32x4* B4 = (const f32x4*)bias_arr;
      int b = tid >> 4, jj4 = tid & 15;
      const f32x4* gp = G4 + ((size_t)blk * 2048 + b * 64) * 16 + jj4;
      const float* ap = attn_s + b * 64;
      f32x4 s = {0.f, 0.f, 0.f, 0.f};
      #pragma unroll 8
      for (int k = 0; k < 64; ++k) {
        float a = ap[k];
        f32x4 g = gp[(size_t)k * 16];
        s[0] += a * g[0]; s[1] += a * g[1]; s[2] += a * g[2]; s[3] += a * g[3];
      }
      f32x4 e = E4[((size_t)blk * 640 + t * 32 + b) * 16 + jj4];
      f32x4 bb = B4[blk * 16 + jj4];
      #pragma unroll
      for (int q = 0; q < 4; ++q) {
        float v = s[q] + (e[q] + bb[q]);
        gsA[(jj4 * 4 + q) * 33 + b] = v;
      }
    }
    // phase 2.5: context fill for batch b = blk (bit-exact k_fill loop)
    {
      const float* aw = attn_s + blk * 64;
      int e = tid;
      if (e < 512) {
        float a = 0.f;
        #pragma unroll 8
        for (int k = 0; k < 64; ++k) a += aw[k] * enc[((size_t)blk * 64 + k) * 512 + e];
        Fall[((size_t)t * 32 + blk) * KIN + 1024 + e] = f2bf_rne(a);
      }
    }
    // phase 3: (W_hh hi/lo) @ h_t, K split across wave pairs (r5 pattern)
    {
      int w = tid >> 6, l = tid & 63, lv = l & 15, lg = l >> 4;
      int g = w & 3, h2 = w >> 2;
      const unsigned short* ah = whh_hi + ((size_t)blk * 64 + g * 16 + lv) * 512 + h2 * 256 + lg * 8;
      const unsigned short* al = whh_lo + ((size_t)blk * 64 + g * 16 + lv) * 512 + h2 * 256 + lg * 8;
      const unsigned short* f0 = Fall + ((size_t)t * 32 + lv) * KIN + h2 * 256 + lg * 8;
      const unsigned short* f1 = Fall + ((size_t)t * 32 + 16 + lv) * KIN + h2 * 256 + lg * 8;
      f32x4 a0 = {0.f, 0.f, 0.f, 0.f};
      f32x4 a1 = {0.f, 0.f, 0.f, 0.f};
      #pragma unroll 8
      for (int kk = 0; kk < 8; ++kk) {
        bf16x8 hi = *(const bf16x8*)(ah + kk * 32);
        bf16x8 lo = *(const bf16x8*)(al + kk * 32);
        bf16x8 b0 = *(const bf16x8*)(f0 + kk * 32);
        bf16x8 b1 = *(const bf16x8*)(f1 + kk * 32);
        a0 = __builtin_amdgcn_mfma_f32_16x16x32_bf16(hi, b0, a0, 0, 0, 0);
        a0 = __builtin_amdgcn_mfma_f32_16x16x32_bf16(lo, b0, a0, 0, 0, 0);
        a1 = __builtin_amdgcn_mfma_f32_16x16x32_bf16(hi, b1, a1, 0, 0, 0);
        a1 = __builtin_amdgcn_mfma_f32_16x16x32_bf16(lo, b1, a1, 0, 0, 0);
      }
      #pragma unroll
      for (int jr = 0; jr < 4; ++jr) {
        int jj = g * 16 + 4 * lg + jr;
        gsH[h2][jj][lv]      = a0[jr];
        gsH[h2][jj][16 + lv] = a1[jr];
      }
    }
    __syncthreads();
    // phase 4: pointwise LSTM + F[t+1] h/c + score partials (one out/thread)
    {
      int b = tid & 31, r = tid >> 5;
      int ii = blk * 16 + r;
      float ig = gsA[(r) * 33 + b]      + gsH[0][r][b]      + gsH[1][r][b];
      float fg = gsA[(16 + r) * 33 + b] + gsH[0][16 + r][b] + gsH[1][16 + r][b];
      float gg = gsA[(32 + r) * 33 + b] + gsH[0][32 + r][b] + gsH[1][32 + r][b];
      float og = gsA[(48 + r) * 33 + b] + gsH[0][48 + r][b] + gsH[1][48 + r][b];
      float cv = cbc[b * H_ + ii];
      float cn = sigm(fg) * cv + sigm(ig) * tanhf(gg);
      float hn = sigm(og) * tanhf(cn);
      cbn[b * H_ + ii] = cn;
      Fall[((size_t)(t + 1) * 32 + b) * KIN + ii] = f2bf_rne(hn);
      Fall[((size_t)(t + 1) * 32 + b) * KIN + H_ + ii] = f2bf_rne(cn);
      scC[r * 32 + b] = hn * Wa[ii] + cn * Wa[512 + ii];
    }
    __syncthreads();
    if (tid < 32) {
      float s = 0.f;
      #pragma unroll
      for (int r = 0; r < 16; ++r) s += scC[r * 32 + tid];
      score_part[(t + 1) * 1024 + blk * 32 + tid] = s;
    }
  } else {
    // ---------- tf==0 slow correctness path: block owns batch b = blk ----
    const int b = blk;
    const float* hbc = hb + (t & 1) * B_ * H_;
    float* hbn = hb + ((t + 1) & 1) * B_ * H_;
    if (tid == 0) {
      float s = 0.f;
      for (int p = 0; p < 32; ++p) s += score_part[t * 1024 + p * 32 + b];
      score_t_[0] = s;
      token_sp = (t == 0) ? captions[b * T_]
                          : (int)(0xFFFFFFFFu - (unsigned)(argkey[b] & 0xFFFFFFFFull));
    }
    __syncthreads();
    if (tid < 64) {
      float s = tanhf(score_t_[0] + enc_score[b * 64 + tid] + ba[0]);
      float m = s;
      for (int o = 32; o; o >>= 1) m = fmaxf(m, __shfl_xor(m, o));
      float e = expf(s - m);
      float sum = e;
      for (int o = 32; o; o >>= 1) sum += __shfl_xor(sum, o);
      attn_s[tid] = e / sum;
    }
    __syncthreads();
    for (int i = tid; i < 512; i += 512) {
      xls[i] = hbc[b * H_ + i];
      xls[512 + i] = cbc[b * H_ + i];
      float a = 0.f;
      for (int k = 0; k < 64; ++k) a += attn_s[k] * enc[((size_t)b * 64 + k) * 512 + i];
      xls[1024 + i] = a;
      xls[1536 + i] = embt[(size_t)token_sp * 512 + i];
    }
    __syncthreads();
    for (int i = tid; i < 1024; i += 512)
      Fall[((size_t)t * 32 + b) * KIN + 1024 + i] = f2bf_rne(xls[1024 + i]);
    for (int j = tid; j < 2048; j += 512) {
      float a = b_ih[j] + b_hh[j];
      for (int e = 0; e < 1024; ++e) a += W_ih[(size_t)j * 1024 + e] * xls[1024 + e];
      for (int e = 0; e < 512; ++e)  a += W_hh[(size_t)j * 512 + e] * xls[e];
      gls[j] = a;
    }
    __syncthreads();
    {
      float sc = 0.f;
      for (int i = tid; i < 512; i += 512) {
        float ig = gls[i], fg = gls[512 + i], gg = gls[1024 + i], og = gls[1536 + i];
        float cv = xls[512 + i];
        float cn = sigm(fg) * cv + sigm(ig) * tanhf(gg);
        float hn = sigm(og) * tanhf(cn);
        hbn[b * H_ + i] = hn;
        cbn[b * H_ + i] = cn;
        Fall[((size_t)(t + 1) * 32 + b) * KIN + i] = f2bf_rne(hn);
        Fall[((size_t)(t + 1) * 32 + b) * KIN + H_ + i] = f2bf_rne(cn);
        sc += hn * Wa[i] + cn * Wa[512 + i];
      }
      scC[tid] = sc;
    }
    __syncthreads();
    if (tid == 0) {
      float s = 0.f;
      for (int q = 0; q < 512; ++q) s += scC[q];
      score_part[(t + 1) * 1024 + b] = s;
    }
    unsigned long long best = 0ull;
    for (int v = tid; v < V_; v += 512) {
      float d = bl[v];
      const float* wr = Wl + (size_t)v * KIN;
      for (int k = 0; k < KIN; ++k) d += wr[k] * xls[k];
      unsigned long long key = ((unsigned long long)ordf(d) << 32) | (0xFFFFFFFFu - (unsigned)v);
      if (key > best) best = key;
    }
    bred[tid] = best;
    __syncthreads();
    for (int o = 256; o; o >>= 1) {
      if (tid < o) bred[tid] = bred[tid] > bred[tid + o] ? bred[tid] : bred[tid + o];
      __syncthreads();
    }
    if (tid == 0) argkey[b] = bred[0];
  }
}

// ---- batched logits GEMM v4: B(Wl)-only LDS, A(F) global (L2-hot) --------
// 500 blocks x 512 thr; block = 64 Wl rows x 640 n (2 passes of 320).
// Same chunk/kq/k MFMA order as proven v2 -> bit-identical logits.
// LDS 2 x 8KB -> 2+ blocks/CU (was 1 at 114KB).
#define GM   64
#define GNP  320
#define BUFB 8192

__global__ __launch_bounds__(512, 2) void k_gemm(
    const unsigned short* __restrict__ wl_bf,
    const unsigned short* __restrict__ F,
    const float* __restrict__ bl,
    float* __restrict__ out) {
  extern __shared__ unsigned char lds[];
  const int tid = threadIdx.x;
  const int l = tid & 63, w = tid >> 6, lv = l & 15, lg = l >> 4;
  const int wm = w >> 2, wn = w & 3;
  const int m0 = blockIdx.x * GM;

  float blv[2];
  #pragma unroll
  for (int mi = 0; mi < 2; ++mi) blv[mi] = bl[m0 + wm * 32 + mi * 16 + lv];

  f32x4 acc[2][5];
  #pragma unroll
  for (int mi = 0; mi < 2; ++mi)
    #pragma unroll
    for (int ni = 0; ni < 5; ++ni) acc[mi][ni] = (f32x4){0.f, 0.f, 0.f, 0.f};

#define STAGE(c, buf) do {                                                    \
    int kb_ = ((c) & 31) * 64;                                                \
    unsigned char* bs_ = lds + (buf) * BUFB;                                  \
    int kq_ = tid >> 6, m_ = tid & 63;                                        \
    gload16(wl_bf + (size_t)(m0 + m_) * KIN + kb_ + kq_ * 8, bs_ + tid * 16); \
  } while (0)

#define COMPUTE(c, buf) do {                                                  \
    int kb_ = ((c) & 31) * 64;                                                \
    int nb_ = ((c) >> 5) * GNP;                                               \
    unsigned char* bs_ = lds + (buf) * BUFB;                                  \
    _Pragma("unroll")                                                         \
    for (int kk2_ = 0; kk2_ < 2; ++kk2_) {                                    \
      int kq_ = kk2_ * 4 + lg;                                                \
      bf16x8 bf_[2];                                                          \
      _Pragma("unroll")                                                       \
      for (int mi = 0; mi < 2; ++mi)                                          \
        bf_[mi] = *(const bf16x8*)(bs_ +                                      \
                    (size_t)(kq_ * 64 + wm * 32 + mi * 16 + lv) * 16);        \
      _Pragma("unroll")                                                       \
      for (int ni = 0; ni < 5; ++ni) {                                        \
        bf16x8 af_ = *(const bf16x8*)(F +                                     \
                    (size_t)(nb_ + wn * 80 + ni * 16 + lv) * KIN +            \
                    kb_ + kq_ * 8);                                           \
        _Pragma("unroll")                                                     \
        for (int mi = 0; mi < 2; ++mi)                                        \
          acc[mi][ni] = __builtin_amdgcn_mfma_f32_16x16x32_bf16(              \
                          af_, bf_[mi], acc[mi][ni], 0, 0, 0);                \
      }                                                                       \
    }                                                                         \
  } while (0)

#define WRITEOUT(pass) do {                                                   \
    _Pragma("unroll")                                                         \
    for (int mi = 0; mi < 2; ++mi) {                                          \
      int v_ = m0 + wm * 32 + mi * 16 + lv;                                   \
      _Pragma("unroll")                                                       \
      for (int ni = 0; ni < 5; ++ni) {                                        \
        _Pragma("unroll")                                                     \
        for (int j_ = 0; j_ < 4; ++j_) {                                      \
          int n_ = (pass) * GNP + wn * 80 + ni * 16 + 4 * lg + j_;            \
          int tt_ = n_ >> 5, bb_ = n_ & 31;                                   \
          out[((size_t)bb_ * T_ + tt_) * V_ + v_] = acc[mi][ni][j_] + blv[mi];\
        }                                                                     \
      }                                                                       \
    }                                                                         \
  } while (0)

  STAGE(0, 0);
  int cur = 0;
  for (int c = 0; c < 64; ++c) {
    __syncthreads();
    if (c < 63) STAGE(c + 1, cur ^ 1);
    COMPUTE(c, cur);
    if (c == 31) {
      WRITEOUT(0);
      #pragma unroll
      for (int mi = 0; mi < 2; ++mi)
        #pragma unroll
        for (int ni = 0; ni < 5; ++ni) acc[mi][ni] = (f32x4){0.f, 0.f, 0.f, 0.f};
    }
    cur ^= 1;
  }
  WRITEOUT(1);
#undef STAGE
#undef COMPUTE
#undef WRITEOUT
}

// ---- final: in-place log_softmax -----------------------------------------
__global__ void k_lsm(float* __restrict__ out) {
  float4* p = (float4*)(out + (size_t)blockIdx.x * V_);
  int tid = threadIdx.x;
  __shared__ float smax[4], ssum[4];
  const int N4 = V_ / 4;
  float m = -1e30f, s = 0.f;
  for (int i = tid; i < N4; i += 256) {
    float4 v = p[i];
    float lm = fmaxf(fmaxf(v.x, v.y), fmaxf(v.z, v.w));
    if (lm > m) { s *= expf(m - lm); m = lm; }
    s += expf(v.x - m) + expf(v.y - m) + expf(v.z - m) + expf(v.w - m);
  }
  for (int o = 32; o; o >>= 1) {
    float m2 = __shfl_xor(m, o), s2 = __shfl_xor(s, o);
    float mn = fmaxf(m, m2);
    s = s * expf(m - mn) + s2 * expf(m2 - mn);
    m = mn;
  }
  if ((tid & 63) == 0) { smax[tid >> 6] = m; ssum[tid >> 6] = s; }
  __syncthreads();
  float mg = fmaxf(fmaxf(smax[0], smax[1]), fmaxf(smax[2], smax[3]));
  float sg = ssum[0] * expf(smax[0] - mg) + ssum[1] * expf(smax[1] - mg)
           + ssum[2] * expf(smax[2] - mg) + ssum[3] * expf(smax[3] - mg);
  float lse = mg + logf(sg);
  for (int i = tid; i < N4; i += 256) {
    float4 v = p[i];
    v.x -= lse; v.y -= lse; v.z -= lse; v.w -= lse;
    p[i] = v;
  }
}

extern "C" void kernel_launch(void* const* d_in, const int* in_sizes, int n_in,
                              void* d_out, int out_size, void* d_ws, size_t ws_size,
                              hipStream_t stream) {
  const float* enc      = (const float*)d_in[0];
  const float* embt     = (const float*)d_in[1];
  const float* Wa       = (const float*)d_in[2];
  const float* ba       = (const float*)d_in[3];
  const float* W_ih     = (const float*)d_in[4];
  const float* W_hh     = (const float*)d_in[5];
  const float* b_ih     = (const float*)d_in[6];
  const float* b_hh     = (const float*)d_in[7];
  const float* Wl       = (const float*)d_in[8];
  const float* bl       = (const float*)d_in[9];
  const int*   captions = (const int*)d_in[10];
  const int*   tf       = (const int*)d_in[11];
  float* out = (float*)d_out;
  char*  ws  = (char*)d_ws;

  size_t off = 0;
  unsigned short* Fall = (unsigned short*)(ws + off); off += (size_t)(T_ + 1) * B_ * KIN * 2;
  float* hb            = (float*)(ws + off);          off += (size_t)2 * B_ * H_ * 4;
  float* cb            = (float*)(ws + off);          off += (size_t)2 * B_ * H_ * 4;
  float* enc_score     = (float*)(ws + off);          off += (size_t)B_ * K_ * 4;
  float* score_part    = (float*)(ws + off);          off += (size_t)(T_ + 1) * 1024 * 4;
  unsigned long long* argkey = (unsigned long long*)(ws + off); off += 256;
  float* bias_arr      = (float*)(ws + off);          off += 2048 * 4;
  off = (off + 1023) & ~(size_t)1023;
  unsigned short* wih_hi = (unsigned short*)(ws + off); off += (size_t)2048 * 1024 * 2;
  unsigned short* wih_lo = (unsigned short*)(ws + off); off += (size_t)2048 * 1024 * 2;
  unsigned short* whh_hi = (unsigned short*)(ws + off); off += (size_t)NBLK * 64 * 512 * 2;
  unsigned short* whh_lo = (unsigned short*)(ws + off); off += (size_t)NBLK * 64 * 512 * 2;
  unsigned short* enc_bf = (unsigned short*)(ws + off); off += (size_t)2048 * 512 * 2;
  unsigned short* emb_bf = (unsigned short*)(ws + off); off += (size_t)640 * 512 * 2;
  float* Genc          = (float*)(ws + off);          off += (size_t)NBLK * 2048 * 64 * 4;
  float* Gemb          = (float*)(ws + off);          off += (size_t)NBLK * 640 * 64 * 4;
  unsigned short* wl_bf = (unsigned short*)(ws + off); off += (size_t)V_ * KIN * 2;

  k_prep<<<512, 256, 0, stream>>>(W_ih, W_hh, b_ih, b_hh, enc, embt, captions,
                                  wih_hi, wih_lo, whh_hi, whh_lo, enc_bf, emb_bf,
                                  bias_arr, score_part, argkey, Fall);
  k_init<<<64, 256, 0, stream>>>(enc, Wa, hb, cb, Fall, enc_score, score_part);
  k_gpre<<<dim3(NBLK, 16), 256, 0, stream>>>(wih_hi, wih_lo, 0, enc_bf, Genc, 2048);
  k_gpre<<<dim3(NBLK, 5), 256, 0, stream>>>(wih_hi, wih_lo, 512, emb_bf, Gemb, 640);

  for (int t = 0; t < T_; ++t) {
    k_step<<<NBLK + NCONV, 512, 0, stream>>>(
        enc, embt, Wa, ba, W_ih, W_hh, b_ih, b_hh,
        Wl, bl, captions, tf, Genc, Gemb,
        whh_hi, whh_lo, bias_arr, enc_score,
        score_part, Fall, hb, cb, argkey, wl_bf, t);
  }
  k_gemm<<<V_ / GM, 512, 2 * BUFB, stream>>>(wl_bf, Fall, bl, out);
  k_lsm<<<B_ * T_, 256, 0, stream>>>(out);
}

// Round 16
// 763.508 us; speedup vs baseline: 1.2139x; 1.2139x over previous
//
#include <hip/hip_runtime.h>
#include <hip/hip_bf16.h>
#include <stdint.h>

#define B_   32
#define K_   64
#define E_   512
#define H_   512
#define M_   512
#define T_   20
#define V_   32000
#define KIN  2048   // 2H + E + M
#define NBLK 32     // chain blocks / j-groups
#define NCONV 224   // conv helper blocks in k_step

typedef __bf16 bf16x8 __attribute__((ext_vector_type(8)));
typedef float  f32x4  __attribute__((ext_vector_type(4)));

__device__ inline unsigned short f2bf_rne(float f) {
  union { float f; unsigned u; } v; v.f = f;
  unsigned r = v.u + 0x7FFFu + ((v.u >> 16) & 1u);
  return (unsigned short)(r >> 16);
}
__device__ inline float bf2f(unsigned short s) {
  union { unsigned u; float f; } v; v.u = ((unsigned)s) << 16;
  return v.f;
}
__device__ inline float sigm(float x) { return 1.f / (1.f + expf(-x)); }
__device__ inline unsigned ordf(float f) {
  unsigned u = __float_as_uint(f);
  return (u & 0x80000000u) ? ~u : (u | 0x80000000u);
}
__device__ __forceinline__ void gload16(const void* g, void* l) {
  __builtin_amdgcn_global_load_lds(
      (const __attribute__((address_space(1))) void*)g,
      (__attribute__((address_space(3))) void*)l, 16, 0, 0);
}

// j-group mapping: block blk owns jj in [0,64): global j = (jj>>4)*512 + blk*16 + (jj&15)

// ---- prep: weight splits, enc/emb bf16, F emb cols, bias, zeros ----------
__global__ void k_prep(const float* __restrict__ W_ih, const float* __restrict__ W_hh,
                       const float* __restrict__ b_ih, const float* __restrict__ b_hh,
                       const float* __restrict__ enc, const float* __restrict__ embt,
                       const int* __restrict__ captions,
                       unsigned short* __restrict__ wih_hi, unsigned short* __restrict__ wih_lo,
                       unsigned short* __restrict__ whh_hi, unsigned short* __restrict__ whh_lo,
                       unsigned short* __restrict__ enc_bf, unsigned short* __restrict__ emb_bf,
                       float* __restrict__ bias_arr, float* __restrict__ score_part,
                       unsigned long long* __restrict__ argkey,
                       unsigned short* __restrict__ Fall) {
  int tid0 = blockIdx.x * 256 + threadIdx.x;
  int NT = gridDim.x * 256;
  for (int i = tid0; i < 2048 * 1024; i += NT) {            // W_ih hi/lo
    float f = W_ih[i];
    unsigned short h = f2bf_rne(f);
    wih_hi[i] = h; wih_lo[i] = f2bf_rne(f - bf2f(h));
  }
  for (int i = tid0; i < NBLK * 64 * 512; i += NT) {        // W_hh rearranged [blk][jj][512]
    int e = i & 511, jj = (i >> 9) & 63, blk = i >> 15;
    int jg = (jj >> 4) * 512 + blk * 16 + (jj & 15);
    float f = W_hh[jg * 512 + e];
    unsigned short h = f2bf_rne(f);
    whh_hi[i] = h; whh_lo[i] = f2bf_rne(f - bf2f(h));
  }
  for (int i = tid0; i < 2048 * 512; i += NT) enc_bf[i] = f2bf_rne(enc[i]);
  for (int i = tid0; i < 640 * 512; i += NT) {              // emb rows + F emb cols (tf=1)
    int n = i >> 9, m = i & 511;
    int t = n >> 5, b = n & 31;
    int tok = captions[b * T_ + (t > 0 ? t - 1 : 0)];
    unsigned short ev = f2bf_rne(embt[(size_t)tok * 512 + m]);
    emb_bf[i] = ev;
    Fall[(size_t)n * KIN + 1536 + m] = ev;
  }
  for (int i = tid0; i < 2048; i += NT) {                   // bias [blk][jj]
    int blk = i >> 6, jj = i & 63;
    int jg = (jj >> 4) * 512 + blk * 16 + (jj & 15);
    bias_arr[i] = b_ih[jg] + b_hh[jg];
  }
  for (int i = tid0; i < (T_ + 1) * 1024; i += NT) score_part[i] = 0.f;
  for (int i = tid0; i < 32; i += NT) argkey[i] = 0ull;
}

// ---- init: h0=c0=enc[:,-1,:], F[0] h/c bf16, enc_score, score_part[0] ----
__global__ void k_init(const float* __restrict__ enc, const float* __restrict__ Wa,
                       float* __restrict__ hb, float* __restrict__ cb,
                       unsigned short* __restrict__ Fall,
                       float* __restrict__ enc_score, float* __restrict__ score_part) {
  int idx = blockIdx.x * 256 + threadIdx.x;   // 64 blocks
  int b = idx >> 9, i = idx & 511;
  float v = enc[(size_t)b * K_ * E_ + (size_t)(K_ - 1) * E_ + i];
  hb[b * H_ + i] = v;
  cb[b * H_ + i] = v;
  unsigned short bv = f2bf_rne(v);
  Fall[b * KIN + i] = bv;
  Fall[b * KIN + H_ + i] = bv;
  if (idx < B_ * K_) {
    int bb = idx >> 6, k = idx & 63;
    const float4* e4  = (const float4*)(enc + ((size_t)bb * K_ + k) * E_);
    const float4* wa4 = (const float4*)(Wa + 2 * H_);
    float acc = 0.f;
    #pragma unroll 4
    for (int q = 0; q < E_ / 4; ++q) {
      float4 a = e4[q], w = wa4[q];
      acc += a.x * w.x + a.y * w.y + a.z * w.z + a.w * w.w;
    }
    enc_score[idx] = acc;
  }
  if (idx < 2048) {     // score_part[0][0][b] = dot([h0,c0], Wa[:1024]), h0=c0
    int bb = idx >> 6, l = idx & 63;
    float s = 0.f;
    #pragma unroll
    for (int q = 0; q < 8; ++q) {
      int ii = l * 8 + q;
      float hv = enc[(size_t)bb * K_ * E_ + (size_t)(K_ - 1) * E_ + ii];
      s += hv * (Wa[ii] + Wa[512 + ii]);
    }
    for (int o = 32; o; o >>= 1) s += __shfl_down(s, o);
    if (l == 0) score_part[bb] = s;
  }
}

// ---- precompute G = (W_ih hi/lo) @ B^T : out[blk][n][jj] fp32 ------------
__global__ __launch_bounds__(256) void k_gpre(
    const unsigned short* __restrict__ whi, const unsigned short* __restrict__ wlo,
    int koff, const unsigned short* __restrict__ Bm,
    float* __restrict__ outp, int N) {
  int blk = blockIdx.x, nt = blockIdx.y;
  int tid = threadIdx.x;
  int l = tid & 63, w = tid >> 6, lv = l & 15, lg = l >> 4;
  const int n0 = nt * 128 + w * 32;

  f32x4 acc[4][2];
  #pragma unroll
  for (int jf = 0; jf < 4; ++jf)
    #pragma unroll
    for (int nf = 0; nf < 2; ++nf) acc[jf][nf] = (f32x4){0.f, 0.f, 0.f, 0.f};

  #pragma unroll 4
  for (int kk = 0; kk < 16; ++kk) {
    bf16x8 bfr[2];
    #pragma unroll
    for (int nf = 0; nf < 2; ++nf)
      bfr[nf] = *(const bf16x8*)(Bm + (size_t)(n0 + nf * 16 + lv) * 512 + kk * 32 + lg * 8);
    #pragma unroll
    for (int jf = 0; jf < 4; ++jf) {
      int jg = jf * 512 + blk * 16 + lv;
      bf16x8 ahi = *(const bf16x8*)(whi + (size_t)jg * 1024 + koff + kk * 32 + lg * 8);
      bf16x8 alo = *(const bf16x8*)(wlo + (size_t)jg * 1024 + koff + kk * 32 + lg * 8);
      #pragma unroll
      for (int nf = 0; nf < 2; ++nf) {
        acc[jf][nf] = __builtin_amdgcn_mfma_f32_16x16x32_bf16(ahi, bfr[nf], acc[jf][nf], 0, 0, 0);
        acc[jf][nf] = __builtin_amdgcn_mfma_f32_16x16x32_bf16(alo, bfr[nf], acc[jf][nf], 0, 0, 0);
      }
    }
  }
  #pragma unroll
  for (int jf = 0; jf < 4; ++jf)
    #pragma unroll
    for (int nf = 0; nf < 2; ++nf)
      #pragma unroll
      for (int jr = 0; jr < 4; ++jr) {
        int n = n0 + nf * 16 + lv;
        int jj = jf * 16 + 4 * lg + jr;
        outp[((size_t)blk * N + n) * 64 + jj] = acc[jf][nf][jr];
      }
}

// ---- per step: blocks 0-31 chain; blocks 32-255 convert Wl slice t -------
__global__ __launch_bounds__(512) void k_step(
    const float* __restrict__ enc, const float* __restrict__ embt,
    const float* __restrict__ Wa, const float* __restrict__ ba,
    const float* __restrict__ W_ih, const float* __restrict__ W_hh,
    const float* __restrict__ b_ih, const float* __restrict__ b_hh,
    const float* __restrict__ Wl, const float* __restrict__ bl,
    const int* __restrict__ captions, const int* __restrict__ tf_flag,
    const float* __restrict__ Genc, const float* __restrict__ Gemb,
    const unsigned short* __restrict__ whh_hi, const unsigned short* __restrict__ whh_lo,
    const float* __restrict__ bias_arr, const float* __restrict__ enc_score,
    float* __restrict__ score_part, unsigned short* __restrict__ Fall,
    float* __restrict__ hb, float* __restrict__ cb,
    unsigned long long* __restrict__ argkey, unsigned short* __restrict__ wl_bf,
    int t) {
  const int blk = blockIdx.x;
  const int tid = threadIdx.x;

  if (blk >= NBLK) {
    // ---- convert Wl slice t (1/20 of the matrix), k_prep's verbatim loop -
    const int NC = V_ * KIN / 4;              // 16,384,000 f32x4's
    const int per = (NC + T_ - 1) / T_;       // 819,200
    int lo = t * per;
    int hi = lo + per; if (hi > NC) hi = NC;
    for (int i = lo + (blk - NBLK) * 512 + tid; i < hi; i += NCONV * 512) {
      f32x4 v = __builtin_nontemporal_load((const f32x4*)Wl + i);
      ushort4 o;
      o.x = f2bf_rne(v.x); o.y = f2bf_rne(v.y); o.z = f2bf_rne(v.z); o.w = f2bf_rne(v.w);
      ((ushort4*)wl_bf)[i] = o;
    }
    return;
  }

  __shared__ float attn_s[B_ * K_];
  __shared__ float gsA[64 * 33];
  __shared__ float gsH[2][64][32];
  __shared__ float scC[512];
  __shared__ float score_t_[32];
  __shared__ int   token_sp;
  __shared__ float xls[KIN];
  __shared__ float gls[2048];
  __shared__ unsigned long long bred[512];
  const float* cbc = cb + (t & 1) * B_ * H_;
  float* cbn = cb + ((t + 1) & 1) * B_ * H_;

  if (tf_flag[0]) {
    // phase 0: assemble scores (deterministic per-slot partials)
    if (tid < 32) {
      float s = 0.f;
      #pragma unroll 8
      for (int p = 0; p < 32; ++p) s += score_part[t * 1024 + p * 32 + tid];
      score_t_[tid] = s;
    }
    __syncthreads();
    // phase 1: softmax (8 waves x 4 batches; lanes = k)
    {
      int w = tid >> 6, l = tid & 63;
      float ba0 = ba[0];
      #pragma unroll
      for (int bb = 0; bb < 4; ++bb) {
        int b = w * 4 + bb;
        float s = tanhf(score_t_[b] + enc_score[b * 64 + l] + ba0);
        float m = s;
        for (int o = 32; o; o >>= 1) m = fmaxf(m, __shfl_xor(m, o));
        float e = expf(s - m);
        float sum = e;
        for (int o = 32; o; o >>= 1) sum += __shfl_xor(sum, o);
        attn_s[b * 64 + l] = e / sum;
      }
    }
    __syncthreads();
    // phase 2: gsA[jj][b] = sum_k attn*Genc + Gemb + bias (one quad/thread)
    {
      const f32x4* G4 = (const f32x4*)Genc;
      const f32x4* E4 = (const f32x4*)Gemb;
      const f32x4* B4 = (const f32x4*)bias_arr;
      int b = tid >> 4, jj4 = tid & 15;
      const f32x4* gp = G4 + ((size_t)blk * 2048 + b * 64) * 16 + jj4;
      const float* ap = attn_s + b * 64;
      f32x4 s = {0.f, 0.f, 0.f, 0.f};
      #pragma unroll 8
      for (int k = 0; k < 64; ++k) {
        float a = ap[k];
        f32x4 g = gp[(size_t)k * 16];
        s[0] += a * g[0]; s[1] += a * g[1]; s[2] += a * g[2]; s[3] += a * g[3];
      }
      f32x4 e = E4[((size_t)blk * 640 + t * 32 + b) * 16 + jj4];
      f32x4 bb = B4[blk * 16 + jj4];
      #pragma unroll
      for (int q = 0; q < 4; ++q) {
        float v = s[q] + (e[q] + bb[q]);
        gsA[(jj4 * 4 + q) * 33 + b] = v;
      }
    }
    // phase 2.5: context fill for batch b = blk (bit-exact k_fill loop)
    {
      const float* aw = attn_s + blk * 64;
      int e = tid;
      if (e < 512) {
        float a = 0.f;
        #pragma unroll 8
        for (int k = 0; k < 64; ++k) a += aw[k] * enc[((size_t)blk * 64 + k) * 512 + e];
        Fall[((size_t)t * 32 + blk) * KIN + 1024 + e] = f2bf_rne(a);
      }
    }
    // phase 3: (W_hh hi/lo) @ h_t, K split across wave pairs (r5 pattern)
    {
      int w = tid >> 6, l = tid & 63, lv = l & 15, lg = l >> 4;
      int g = w & 3, h2 = w >> 2;
      const unsigned short* ah = whh_hi + ((size_t)blk * 64 + g * 16 + lv) * 512 + h2 * 256 + lg * 8;
      const unsigned short* al = whh_lo + ((size_t)blk * 64 + g * 16 + lv) * 512 + h2 * 256 + lg * 8;
      const unsigned short* f0 = Fall + ((size_t)t * 32 + lv) * KIN + h2 * 256 + lg * 8;
      const unsigned short* f1 = Fall + ((size_t)t * 32 + 16 + lv) * KIN + h2 * 256 + lg * 8;
      f32x4 a0 = {0.f, 0.f, 0.f, 0.f};
      f32x4 a1 = {0.f, 0.f, 0.f, 0.f};
      #pragma unroll 8
      for (int kk = 0; kk < 8; ++kk) {
        bf16x8 hi = *(const bf16x8*)(ah + kk * 32);
        bf16x8 lo = *(const bf16x8*)(al + kk * 32);
        bf16x8 b0 = *(const bf16x8*)(f0 + kk * 32);
        bf16x8 b1 = *(const bf16x8*)(f1 + kk * 32);
        a0 = __builtin_amdgcn_mfma_f32_16x16x32_bf16(hi, b0, a0, 0, 0, 0);
        a0 = __builtin_amdgcn_mfma_f32_16x16x32_bf16(lo, b0, a0, 0, 0, 0);
        a1 = __builtin_amdgcn_mfma_f32_16x16x32_bf16(hi, b1, a1, 0, 0, 0);
        a1 = __builtin_amdgcn_mfma_f32_16x16x32_bf16(lo, b1, a1, 0, 0, 0);
      }
      #pragma unroll
      for (int jr = 0; jr < 4; ++jr) {
        int jj = g * 16 + 4 * lg + jr;
        gsH[h2][jj][lv]      = a0[jr];
        gsH[h2][jj][16 + lv] = a1[jr];
      }
    }
    __syncthreads();
    // phase 4: pointwise LSTM + F[t+1] h/c + score partials (one out/thread)
    {
      int b = tid & 31, r = tid >> 5;
      int ii = blk * 16 + r;
      float ig = gsA[(r) * 33 + b]      + gsH[0][r][b]      + gsH[1][r][b];
      float fg = gsA[(16 + r) * 33 + b] + gsH[0][16 + r][b] + gsH[1][16 + r][b];
      float gg = gsA[(32 + r) * 33 + b] + gsH[0][32 + r][b] + gsH[1][32 + r][b];
      float og = gsA[(48 + r) * 33 + b] + gsH[0][48 + r][b] + gsH[1][48 + r][b];
      float cv = cbc[b * H_ + ii];
      float cn = sigm(fg) * cv + sigm(ig) * tanhf(gg);
      float hn = sigm(og) * tanhf(cn);
      cbn[b * H_ + ii] = cn;
      Fall[((size_t)(t + 1) * 32 + b) * KIN + ii] = f2bf_rne(hn);
      Fall[((size_t)(t + 1) * 32 + b) * KIN + H_ + ii] = f2bf_rne(cn);
      scC[r * 32 + b] = hn * Wa[ii] + cn * Wa[512 + ii];
    }
    __syncthreads();
    if (tid < 32) {
      float s = 0.f;
      #pragma unroll
      for (int r = 0; r < 16; ++r) s += scC[r * 32 + tid];
      score_part[(t + 1) * 1024 + blk * 32 + tid] = s;
    }
  } else {
    // ---------- tf==0 slow correctness path: block owns batch b = blk ----
    const int b = blk;
    const float* hbc = hb + (t & 1) * B_ * H_;
    float* hbn = hb + ((t + 1) & 1) * B_ * H_;
    if (tid == 0) {
      float s = 0.f;
      for (int p = 0; p < 32; ++p) s += score_part[t * 1024 + p * 32 + b];
      score_t_[0] = s;
      token_sp = (t == 0) ? captions[b * T_]
                          : (int)(0xFFFFFFFFu - (unsigned)(argkey[b] & 0xFFFFFFFFull));
    }
    __syncthreads();
    if (tid < 64) {
      float s = tanhf(score_t_[0] + enc_score[b * 64 + tid] + ba[0]);
      float m = s;
      for (int o = 32; o; o >>= 1) m = fmaxf(m, __shfl_xor(m, o));
      float e = expf(s - m);
      float sum = e;
      for (int o = 32; o; o >>= 1) sum += __shfl_xor(sum, o);
      attn_s[tid] = e / sum;
    }
    __syncthreads();
    for (int i = tid; i < 512; i += 512) {
      xls[i] = hbc[b * H_ + i];
      xls[512 + i] = cbc[b * H_ + i];
      float a = 0.f;
      for (int k = 0; k < 64; ++k) a += attn_s[k] * enc[((size_t)b * 64 + k) * 512 + i];
      xls[1024 + i] = a;
      xls[1536 + i] = embt[(size_t)token_sp * 512 + i];
    }
    __syncthreads();
    for (int i = tid; i < 1024; i += 512)
      Fall[((size_t)t * 32 + b) * KIN + 1024 + i] = f2bf_rne(xls[1024 + i]);
    for (int j = tid; j < 2048; j += 512) {
      float a = b_ih[j] + b_hh[j];
      for (int e = 0; e < 1024; ++e) a += W_ih[(size_t)j * 1024 + e] * xls[1024 + e];
      for (int e = 0; e < 512; ++e)  a += W_hh[(size_t)j * 512 + e] * xls[e];
      gls[j] = a;
    }
    __syncthreads();
    {
      float sc = 0.f;
      for (int i = tid; i < 512; i += 512) {
        float ig = gls[i], fg = gls[512 + i], gg = gls[1024 + i], og = gls[1536 + i];
        float cv = xls[512 + i];
        float cn = sigm(fg) * cv + sigm(ig) * tanhf(gg);
        float hn = sigm(og) * tanhf(cn);
        hbn[b * H_ + i] = hn;
        cbn[b * H_ + i] = cn;
        Fall[((size_t)(t + 1) * 32 + b) * KIN + i] = f2bf_rne(hn);
        Fall[((size_t)(t + 1) * 32 + b) * KIN + H_ + i] = f2bf_rne(cn);
        sc += hn * Wa[i] + cn * Wa[512 + i];
      }
      scC[tid] = sc;
    }
    __syncthreads();
    if (tid == 0) {
      float s = 0.f;
      for (int q = 0; q < 512; ++q) s += scC[q];
      score_part[(t + 1) * 1024 + b] = s;
    }
    unsigned long long best = 0ull;
    for (int v = tid; v < V_; v += 512) {
      float d = bl[v];
      const float* wr = Wl + (size_t)v * KIN;
      for (int k = 0; k < KIN; ++k) d += wr[k] * xls[k];
      unsigned long long key = ((unsigned long long)ordf(d) << 32) | (0xFFFFFFFFu - (unsigned)v);
      if (key > best) best = key;
    }
    bred[tid] = best;
    __syncthreads();
    for (int o = 256; o; o >>= 1) {
      if (tid < o) bred[tid] = bred[tid] > bred[tid + o] ? bred[tid] : bred[tid + o];
      __syncthreads();
    }
    if (tid == 0) argkey[b] = bred[0];
  }
}

// ---- batched logits GEMM (proven v2): C[v][n] = Wl[v]·F[n] ---------------
#define GM   128
#define GNP  320
#define ABYTES 40960
#define BUFB  57344

__global__ __launch_bounds__(512, 2) void k_gemm(
    const unsigned short* __restrict__ wl_bf,
    const unsigned short* __restrict__ F,
    const float* __restrict__ bl,
    float* __restrict__ out) {
  extern __shared__ unsigned char lds[];
  const int tid = threadIdx.x;
  const int l = tid & 63, w = tid >> 6, lv = l & 15, lg = l >> 4;
  const int wm = w >> 2, wn = w & 3;
  const int m0 = blockIdx.x * GM;

  float blv[4];
  #pragma unroll
  for (int mi = 0; mi < 4; ++mi) blv[mi] = bl[m0 + wm * 64 + mi * 16 + lv];

  f32x4 acc[4][5];
  #pragma unroll
  for (int mi = 0; mi < 4; ++mi)
    #pragma unroll
    for (int ni = 0; ni < 5; ++ni) acc[mi][ni] = (f32x4){0.f, 0.f, 0.f, 0.f};

#define STAGE(c, buf) do {                                                    \
    int kb_ = ((c) & 31) * 64;                                                \
    int nb_ = ((c) >> 5) * GNP;                                               \
    unsigned char* bs_ = lds + (buf) * BUFB;                                  \
    _Pragma("unroll")                                                         \
    for (int i_ = 0; i_ < 5; ++i_) {                                          \
      int s_ = i_ * 512 + tid;                                                \
      int kq_ = s_ / 320, n_ = s_ - kq_ * 320;                                \
      gload16(F + (size_t)(nb_ + n_) * KIN + kb_ + kq_ * 8, bs_ + s_ * 16);   \
    }                                                                         \
    _Pragma("unroll")                                                         \
    for (int j_ = 0; j_ < 2; ++j_) {                                          \
      int s_ = j_ * 512 + tid;                                                \
      int kq_ = s_ >> 7, m_ = s_ & 127;                                       \
      gload16(wl_bf + (size_t)(m0 + m_) * KIN + kb_ + kq_ * 8,                \
              bs_ + ABYTES + s_ * 16);                                        \
    }                                                                         \
  } while (0)

#define COMPUTE(buf) do {                                                     \
    unsigned char* bs_ = lds + (buf) * BUFB;                                  \
    _Pragma("unroll")                                                         \
    for (int kk2_ = 0; kk2_ < 2; ++kk2_) {                                    \
      int kq_ = kk2_ * 4 + lg;                                                \
      bf16x8 bf_[4];                                                          \
      _Pragma("unroll")                                                       \
      for (int mi = 0; mi < 4; ++mi)                                          \
        bf_[mi] = *(const bf16x8*)(bs_ + ABYTES +                             \
                    (size_t)(kq_ * 128 + wm * 64 + mi * 16 + lv) * 16);       \
      _Pragma("unroll")                                                       \
      for (int ni = 0; ni < 5; ++ni) {                                        \
        bf16x8 af_ = *(const bf16x8*)(bs_ +                                   \
                    (size_t)(kq_ * 320 + wn * 80 + ni * 16 + lv) * 16);       \
        _Pragma("unroll")                                                     \
        for (int mi = 0; mi < 4; ++mi)                                        \
          acc[mi][ni] = __builtin_amdgcn_mfma_f32_16x16x32_bf16(              \
                          af_, bf_[mi], acc[mi][ni], 0, 0, 0);                \
      }                                                                       \
    }                                                                         \
  } while (0)

#define WRITEOUT(pass) do {                                                   \
    _Pragma("unroll")                                                         \
    for (int mi = 0; mi < 4; ++mi) {                                          \
      int v_ = m0 + wm * 64 + mi * 16 + lv;                                   \
      _Pragma("unroll")                                                       \
      for (int ni = 0; ni < 5; ++ni) {                                        \
        _Pragma("unroll")                                                     \
        for (int j_ = 0; j_ < 4; ++j_) {                                      \
          int n_ = (pass) * GNP + wn * 80 + ni * 16 + 4 * lg + j_;            \
          int tt_ = n_ >> 5, bb_ = n_ & 31;                                   \
          out[((size_t)bb_ * T_ + tt_) * V_ + v_] = acc[mi][ni][j_] + blv[mi];\
        }                                                                     \
      }                                                                       \
    }                                                                         \
  } while (0)

  STAGE(0, 0);
  int cur = 0;
  for (int c = 0; c < 64; ++c) {
    __syncthreads();
    if (c < 63) STAGE(c + 1, cur ^ 1);
    COMPUTE(cur);
    if (c == 31) {
      WRITEOUT(0);
      #pragma unroll
      for (int mi = 0; mi < 4; ++mi)
        #pragma unroll
        for (int ni = 0; ni < 5; ++ni) acc[mi][ni] = (f32x4){0.f, 0.f, 0.f, 0.f};
    }
    cur ^= 1;
  }
  WRITEOUT(1);
#undef STAGE
#undef COMPUTE
#undef WRITEOUT
}

// ---- final: in-place log_softmax -----------------------------------------
__global__ void k_lsm(float* __restrict__ out) {
  float4* p = (float4*)(out + (size_t)blockIdx.x * V_);
  int tid = threadIdx.x;
  __shared__ float smax[4], ssum[4];
  const int N4 = V_ / 4;
  float m = -1e30f, s = 0.f;
  for (int i = tid; i < N4; i += 256) {
    float4 v = p[i];
    float lm = fmaxf(fmaxf(v.x, v.y), fmaxf(v.z, v.w));
    if (lm > m) { s *= expf(m - lm); m = lm; }
    s += expf(v.x - m) + expf(v.y - m) + expf(v.z - m) + expf(v.w - m);
  }
  for (int o = 32; o; o >>= 1) {
    float m2 = __shfl_xor(m, o), s2 = __shfl_xor(s, o);
    float mn = fmaxf(m, m2);
    s = s * expf(m - mn) + s2 * expf(m2 - mn);
    m = mn;
  }
  if ((tid & 63) == 0) { smax[tid >> 6] = m; ssum[tid >> 6] = s; }
  __syncthreads();
  float mg = fmaxf(fmaxf(smax[0], smax[1]), fmaxf(smax[2], smax[3]));
  float sg = ssum[0] * expf(smax[0] - mg) + ssum[1] * expf(smax[1] - mg)
           + ssum[2] * expf(smax[2] - mg) + ssum[3] * expf(smax[3] - mg);
  float lse = mg + logf(sg);
  for (int i = tid; i < N4; i += 256) {
    float4 v = p[i];
    v.x -= lse; v.y -= lse; v.z -= lse; v.w -= lse;
    p[i] = v;
  }
}

extern "C" void kernel_launch(void* const* d_in, const int* in_sizes, int n_in,
                              void* d_out, int out_size, void* d_ws, size_t ws_size,
                              hipStream_t stream) {
  const float* enc      = (const float*)d_in[0];
  const float* embt     = (const float*)d_in[1];
  const float* Wa       = (const float*)d_in[2];
  const float* ba       = (const float*)d_in[3];
  const float* W_ih     = (const float*)d_in[4];
  const float* W_hh     = (const float*)d_in[5];
  const float* b_ih     = (const float*)d_in[6];
  const float* b_hh     = (const float*)d_in[7];
  const float* Wl       = (const float*)d_in[8];
  const float* bl       = (const float*)d_in[9];
  const int*   captions = (const int*)d_in[10];
  const int*   tf       = (const int*)d_in[11];
  float* out = (float*)d_out;
  char*  ws  = (char*)d_ws;

  size_t off = 0;
  unsigned short* Fall = (unsigned short*)(ws + off); off += (size_t)(T_ + 1) * B_ * KIN * 2;
  float* hb            = (float*)(ws + off);          off += (size_t)2 * B_ * H_ * 4;
  float* cb            = (float*)(ws + off);          off += (size_t)2 * B_ * H_ * 4;
  float* enc_score     = (float*)(ws + off);          off += (size_t)B_ * K_ * 4;
  float* score_part    = (float*)(ws + off);          off += (size_t)(T_ + 1) * 1024 * 4;
  unsigned long long* argkey = (unsigned long long*)(ws + off); off += 256;
  float* bias_arr      = (float*)(ws + off);          off += 2048 * 4;
  off = (off + 1023) & ~(size_t)1023;
  unsigned short* wih_hi = (unsigned short*)(ws + off); off += (size_t)2048 * 1024 * 2;
  unsigned short* wih_lo = (unsigned short*)(ws + off); off += (size_t)2048 * 1024 * 2;
  unsigned short* whh_hi = (unsigned short*)(ws + off); off += (size_t)NBLK * 64 * 512 * 2;
  unsigned short* whh_lo = (unsigned short*)(ws + off); off += (size_t)NBLK * 64 * 512 * 2;
  unsigned short* enc_bf = (unsigned short*)(ws + off); off += (size_t)2048 * 512 * 2;
  unsigned short* emb_bf = (unsigned short*)(ws + off); off += (size_t)640 * 512 * 2;
  float* Genc          = (float*)(ws + off);          off += (size_t)NBLK * 2048 * 64 * 4;
  float* Gemb          = (float*)(ws + off);          off += (size_t)NBLK * 640 * 64 * 4;
  unsigned short* wl_bf = (unsigned short*)(ws + off); off += (size_t)V_ * KIN * 2;

  k_prep<<<512, 256, 0, stream>>>(W_ih, W_hh, b_ih, b_hh, enc, embt, captions,
                                  wih_hi, wih_lo, whh_hi, whh_lo, enc_bf, emb_bf,
                                  bias_arr, score_part, argkey, Fall);
  k_init<<<64, 256, 0, stream>>>(enc, Wa, hb, cb, Fall, enc_score, score_part);
  k_gpre<<<dim3(NBLK, 16), 256, 0, stream>>>(wih_hi, wih_lo, 0, enc_bf, Genc, 2048);
  k_gpre<<<dim3(NBLK, 5), 256, 0, stream>>>(wih_hi, wih_lo, 512, emb_bf, Gemb, 640);

  for (int t = 0; t < T_; ++t) {
    k_step<<<NBLK + NCONV, 512, 0, stream>>>(
        enc, embt, Wa, ba, W_ih, W_hh, b_ih, b_hh,
        Wl, bl, captions, tf, Genc, Gemb,
        whh_hi, whh_lo, bias_arr, enc_score,
        score_part, Fall, hb, cb, argkey, wl_bf, t);
  }
  k_gemm<<<V_ / GM, 512, 2 * BUFB, stream>>>(wl_bf, Fall, bl, out);
  k_lsm<<<B_ * T_, 256, 0, stream>>>(out);
}

// Round 18
// 742.332 us; speedup vs baseline: 1.2485x; 1.0285x over previous
//
#include <hip/hip_runtime.h>
#include <hip/hip_bf16.h>
#include <stdint.h>

#define B_   32
#define K_   64
#define E_   512
#define H_   512
#define M_   512
#define T_   20
#define V_   32000
#define KIN  2048   // 2H + E + M
#define NBLK 32     // chain blocks / j-groups
#define NCONV 224   // conv helper blocks in k_step

typedef __bf16 bf16x8 __attribute__((ext_vector_type(8)));
typedef float  f32x4  __attribute__((ext_vector_type(4)));

__device__ inline unsigned short f2bf_rne(float f) {
  union { float f; unsigned u; } v; v.f = f;
  unsigned r = v.u + 0x7FFFu + ((v.u >> 16) & 1u);
  return (unsigned short)(r >> 16);
}
__device__ inline float bf2f(unsigned short s) {
  union { unsigned u; float f; } v; v.u = ((unsigned)s) << 16;
  return v.f;
}
__device__ inline float sigm(float x) { return 1.f / (1.f + expf(-x)); }
__device__ inline unsigned ordf(float f) {
  unsigned u = __float_as_uint(f);
  return (u & 0x80000000u) ? ~u : (u | 0x80000000u);
}
__device__ __forceinline__ void gload16(const void* g, void* l) {
  __builtin_amdgcn_global_load_lds(
      (const __attribute__((address_space(1))) void*)g,
      (__attribute__((address_space(3))) void*)l, 16, 0, 0);
}

// j-group mapping: block blk owns jj in [0,64): global j = (jj>>4)*512 + blk*16 + (jj&15)

// ---- prep (+init merged): weight splits, enc/emb bf16, F emb cols, bias,
//      zeros, h0/c0, F[0] h/c, enc_score, score_part[0] --------------------
// Disjointness: init-part writes Fall[rows 0..31][0..1024), score_part[0..31];
// prep-part writes Fall[*][1536..2048), score_part[32..) (zero loop skips <32).
__global__ void k_prep(const float* __restrict__ W_ih, const float* __restrict__ W_hh,
                       const float* __restrict__ b_ih, const float* __restrict__ b_hh,
                       const float* __restrict__ enc, const float* __restrict__ embt,
                       const float* __restrict__ Wa, const int* __restrict__ captions,
                       unsigned short* __restrict__ wih_hi, unsigned short* __restrict__ wih_lo,
                       unsigned short* __restrict__ whh_hi, unsigned short* __restrict__ whh_lo,
                       unsigned short* __restrict__ enc_bf, unsigned short* __restrict__ emb_bf,
                       float* __restrict__ bias_arr, float* __restrict__ score_part,
                       unsigned long long* __restrict__ argkey,
                       float* __restrict__ hb, float* __restrict__ cb,
                       float* __restrict__ enc_score,
                       unsigned short* __restrict__ Fall) {
  int tid0 = blockIdx.x * 256 + threadIdx.x;
  int NT = gridDim.x * 256;
  for (int i = tid0; i < 2048 * 1024; i += NT) {            // W_ih hi/lo
    float f = W_ih[i];
    unsigned short h = f2bf_rne(f);
    wih_hi[i] = h; wih_lo[i] = f2bf_rne(f - bf2f(h));
  }
  for (int i = tid0; i < NBLK * 64 * 512; i += NT) {        // W_hh rearranged [blk][jj][512]
    int e = i & 511, jj = (i >> 9) & 63, blk = i >> 15;
    int jg = (jj >> 4) * 512 + blk * 16 + (jj & 15);
    float f = W_hh[jg * 512 + e];
    unsigned short h = f2bf_rne(f);
    whh_hi[i] = h; whh_lo[i] = f2bf_rne(f - bf2f(h));
  }
  for (int i = tid0; i < 2048 * 512; i += NT) enc_bf[i] = f2bf_rne(enc[i]);
  for (int i = tid0; i < 640 * 512; i += NT) {              // emb rows + F emb cols (tf=1)
    int n = i >> 9, m = i & 511;
    int t = n >> 5, b = n & 31;
    int tok = captions[b * T_ + (t > 0 ? t - 1 : 0)];
    unsigned short ev = f2bf_rne(embt[(size_t)tok * 512 + m]);
    emb_bf[i] = ev;
    Fall[(size_t)n * KIN + 1536 + m] = ev;
  }
  for (int i = tid0; i < 2048; i += NT) {                   // bias [blk][jj]
    int blk = i >> 6, jj = i & 63;
    int jg = (jj >> 4) * 512 + blk * 16 + (jj & 15);
    bias_arr[i] = b_ih[jg] + b_hh[jg];
  }
  for (int i = tid0; i < (T_ + 1) * 1024; i += NT)
    if (i >= 32) score_part[i] = 0.f;                       // init owns [0,32)
  for (int i = tid0; i < 32; i += NT) argkey[i] = 0ull;

  // ---- merged k_init (blocks 0..63; same idx mapping as before) ----------
  if (blockIdx.x < 64) {
    int idx = blockIdx.x * 256 + threadIdx.x;
    int b = idx >> 9, i = idx & 511;
    float v = enc[(size_t)b * K_ * E_ + (size_t)(K_ - 1) * E_ + i];
    hb[b * H_ + i] = v;
    cb[b * H_ + i] = v;
    unsigned short bv = f2bf_rne(v);
    Fall[b * KIN + i] = bv;
    Fall[b * KIN + H_ + i] = bv;
    if (idx < B_ * K_) {
      int bb = idx >> 6, k = idx & 63;
      const float4* e4  = (const float4*)(enc + ((size_t)bb * K_ + k) * E_);
      const float4* wa4 = (const float4*)(Wa + 2 * H_);
      float acc = 0.f;
      #pragma unroll 4
      for (int q = 0; q < E_ / 4; ++q) {
        float4 a = e4[q], w = wa4[q];
        acc += a.x * w.x + a.y * w.y + a.z * w.z + a.w * w.w;
      }
      enc_score[idx] = acc;
    }
    if (idx < 2048) {   // score_part[0][0][b] = dot([h0,c0], Wa[:1024]), h0=c0
      int bb = idx >> 6, l = idx & 63;
      float s = 0.f;
      #pragma unroll
      for (int q = 0; q < 8; ++q) {
        int ii = l * 8 + q;
        float hv = enc[(size_t)bb * K_ * E_ + (size_t)(K_ - 1) * E_ + ii];
        s += hv * (Wa[ii] + Wa[512 + ii]);
      }
      for (int o = 32; o; o >>= 1) s += __shfl_down(s, o);
      if (l == 0) score_part[bb] = s;
    }
  }
}

// ---- precompute G = (W_ih hi/lo) @ B^T, enc+emb merged via blockIdx.y ----
// y<16: enc (N=2048, koff=0, out=Genc); y>=16: emb (N=640, koff=512, Gemb).
__global__ __launch_bounds__(256) void k_gpre(
    const unsigned short* __restrict__ whi, const unsigned short* __restrict__ wlo,
    const unsigned short* __restrict__ enc_bf, const unsigned short* __restrict__ emb_bf,
    float* __restrict__ Genc, float* __restrict__ Gemb) {
  int blk = blockIdx.x;
  int nt = blockIdx.y;
  const unsigned short* Bm;
  float* outp;
  int N, koff;
  if (nt < 16) { Bm = enc_bf; outp = Genc; N = 2048; koff = 0; }
  else         { Bm = emb_bf; outp = Gemb; N = 640;  koff = 512; nt -= 16; }
  int tid = threadIdx.x;
  int l = tid & 63, w = tid >> 6, lv = l & 15, lg = l >> 4;
  const int n0 = nt * 128 + w * 32;

  f32x4 acc[4][2];
  #pragma unroll
  for (int jf = 0; jf < 4; ++jf)
    #pragma unroll
    for (int nf = 0; nf < 2; ++nf) acc[jf][nf] = (f32x4){0.f, 0.f, 0.f, 0.f};

  #pragma unroll 4
  for (int kk = 0; kk < 16; ++kk) {
    bf16x8 bfr[2];
    #pragma unroll
    for (int nf = 0; nf < 2; ++nf)
      bfr[nf] = *(const bf16x8*)(Bm + (size_t)(n0 + nf * 16 + lv) * 512 + kk * 32 + lg * 8);
    #pragma unroll
    for (int jf = 0; jf < 4; ++jf) {
      int jg = jf * 512 + blk * 16 + lv;
      bf16x8 ahi = *(const bf16x8*)(whi + (size_t)jg * 1024 + koff + kk * 32 + lg * 8);
      bf16x8 alo = *(const bf16x8*)(wlo + (size_t)jg * 1024 + koff + kk * 32 + lg * 8);
      #pragma unroll
      for (int nf = 0; nf < 2; ++nf) {
        acc[jf][nf] = __builtin_amdgcn_mfma_f32_16x16x32_bf16(ahi, bfr[nf], acc[jf][nf], 0, 0, 0);
        acc[jf][nf] = __builtin_amdgcn_mfma_f32_16x16x32_bf16(alo, bfr[nf], acc[jf][nf], 0, 0, 0);
      }
    }
  }
  #pragma unroll
  for (int jf = 0; jf < 4; ++jf)
    #pragma unroll
    for (int nf = 0; nf < 2; ++nf)
      #pragma unroll
      for (int jr = 0; jr < 4; ++jr) {
        int n = n0 + nf * 16 + lv;
        int jj = jf * 16 + 4 * lg + jr;
        outp[((size_t)blk * N + n) * 64 + jj] = acc[jf][nf][jr];
      }
}

// ---- per step: blocks 0-31 chain; blocks 32-255 convert Wl slice t -------
__global__ __launch_bounds__(512) void k_step(
    const float* __restrict__ enc, const float* __restrict__ embt,
    const float* __restrict__ Wa, const float* __restrict__ ba,
    const float* __restrict__ W_ih, const float* __restrict__ W_hh,
    const float* __restrict__ b_ih, const float* __restrict__ b_hh,
    const float* __restrict__ Wl, const float* __restrict__ bl,
    const int* __restrict__ captions, const int* __restrict__ tf_flag,
    const float* __restrict__ Genc, const float* __restrict__ Gemb,
    const unsigned short* __restrict__ whh_hi, const unsigned short* __restrict__ whh_lo,
    const float* __restrict__ bias_arr, const float* __restrict__ enc_score,
    float* __restrict__ score_part, unsigned short* __restrict__ Fall,
    float* __restrict__ hb, float* __restrict__ cb,
    unsigned long long* __restrict__ argkey, unsigned short* __restrict__ wl_bf,
    int t) {
  const int blk = blockIdx.x;
  const int tid = threadIdx.x;

  if (blk >= NBLK) {
    // ---- convert Wl slice t (1/20 of the matrix), k_prep's verbatim loop -
    const int NC = V_ * KIN / 4;              // 16,384,000 f32x4's
    const int per = (NC + T_ - 1) / T_;       // 819,200
    int lo = t * per;
    int hi = lo + per; if (hi > NC) hi = NC;
    for (int i = lo + (blk - NBLK) * 512 + tid; i < hi; i += NCONV * 512) {
      f32x4 v = __builtin_nontemporal_load((const f32x4*)Wl + i);
      ushort4 o;
      o.x = f2bf_rne(v.x); o.y = f2bf_rne(v.y); o.z = f2bf_rne(v.z); o.w = f2bf_rne(v.w);
      ((ushort4*)wl_bf)[i] = o;
    }
    return;
  }

  __shared__ float attn_s[B_ * K_];
  __shared__ float gsA[64 * 33];
  __shared__ float gsH[2][64][32];
  __shared__ float scC[512];
  __shared__ float score_t_[32];
  __shared__ int   token_sp;
  __shared__ float xls[KIN];
  __shared__ float gls[2048];
  __shared__ unsigned long long bred[512];
  const float* cbc = cb + (t & 1) * B_ * H_;
  float* cbn = cb + ((t + 1) & 1) * B_ * H_;

  if (tf_flag[0]) {
    // phase 0: assemble scores (deterministic per-slot partials)
    if (tid < 32) {
      float s = 0.f;
      #pragma unroll 8
      for (int p = 0; p < 32; ++p) s += score_part[t * 1024 + p * 32 + tid];
      score_t_[tid] = s;
    }
    __syncthreads();
    // phase 1: softmax (8 waves x 4 batches; lanes = k)
    {
      int w = tid >> 6, l = tid & 63;
      float ba0 = ba[0];
      #pragma unroll
      for (int bb = 0; bb < 4; ++bb) {
        int b = w * 4 + bb;
        float s = tanhf(score_t_[b] + enc_score[b * 64 + l] + ba0);
        float m = s;
        for (int o = 32; o; o >>= 1) m = fmaxf(m, __shfl_xor(m, o));
        float e = expf(s - m);
        float sum = e;
        for (int o = 32; o; o >>= 1) sum += __shfl_xor(sum, o);
        attn_s[b * 64 + l] = e / sum;
      }
    }
    __syncthreads();
    // phase 2: gsA[jj][b] = sum_k attn*Genc + Gemb + bias (one quad/thread)
    {
      const f32x4* G4 = (const f32x4*)Genc;
      const f32x4* E4 = (const f32x4*)Gemb;
      const f32x4* B4 = (const f32x4*)bias_arr;
      int b = tid >> 4, jj4 = tid & 15;
      const f32x4* gp = G4 + ((size_t)blk * 2048 + b * 64) * 16 + jj4;
      const float* ap = attn_s + b * 64;
      f32x4 s = {0.f, 0.f, 0.f, 0.f};
      #pragma unroll 8
      for (int k = 0; k < 64; ++k) {
        float a = ap[k];
        f32x4 g = gp[(size_t)k * 16];
        s[0] += a * g[0]; s[1] += a * g[1]; s[2] += a * g[2]; s[3] += a * g[3];
      }
      f32x4 e = E4[((size_t)blk * 640 + t * 32 + b) * 16 + jj4];
      f32x4 bb = B4[blk * 16 + jj4];
      #pragma unroll
      for (int q = 0; q < 4; ++q) {
        float v = s[q] + (e[q] + bb[q]);
        gsA[(jj4 * 4 + q) * 33 + b] = v;
      }
    }
    // phase 2.5: context fill for batch b = blk (bit-exact k_fill loop)
    {
      const float* aw = attn_s + blk * 64;
      int e = tid;
      if (e < 512) {
        float a = 0.f;
        #pragma unroll 8
        for (int k = 0; k < 64; ++k) a += aw[k] * enc[((size_t)blk * 64 + k) * 512 + e];
        Fall[((size_t)t * 32 + blk) * KIN + 1024 + e] = f2bf_rne(a);
      }
    }
    // phase 3: (W_hh hi/lo) @ h_t, K split across wave pairs (r5 pattern)
    {
      int w = tid >> 6, l = tid & 63, lv = l & 15, lg = l >> 4;
      int g = w & 3, h2 = w >> 2;
      const unsigned short* ah = whh_hi + ((size_t)blk * 64 + g * 16 + lv) * 512 + h2 * 256 + lg * 8;
      const unsigned short* al = whh_lo + ((size_t)blk * 64 + g * 16 + lv) * 512 + h2 * 256 + lg * 8;
      const unsigned short* f0 = Fall + ((size_t)t * 32 + lv) * KIN + h2 * 256 + lg * 8;
      const unsigned short* f1 = Fall + ((size_t)t * 32 + 16 + lv) * KIN + h2 * 256 + lg * 8;
      f32x4 a0 = {0.f, 0.f, 0.f, 0.f};
      f32x4 a1 = {0.f, 0.f, 0.f, 0.f};
      #pragma unroll 8
      for (int kk = 0; kk < 8; ++kk) {
        bf16x8 hi = *(const bf16x8*)(ah + kk * 32);
        bf16x8 lo = *(const bf16x8*)(al + kk * 32);
        bf16x8 b0 = *(const bf16x8*)(f0 + kk * 32);
        bf16x8 b1 = *(const bf16x8*)(f1 + kk * 32);
        a0 = __builtin_amdgcn_mfma_f32_16x16x32_bf16(hi, b0, a0, 0, 0, 0);
        a0 = __builtin_amdgcn_mfma_f32_16x16x32_bf16(lo, b0, a0, 0, 0, 0);
        a1 = __builtin_amdgcn_mfma_f32_16x16x32_bf16(hi, b1, a1, 0, 0, 0);
        a1 = __builtin_amdgcn_mfma_f32_16x16x32_bf16(lo, b1, a1, 0, 0, 0);
      }
      #pragma unroll
      for (int jr = 0; jr < 4; ++jr) {
        int jj = g * 16 + 4 * lg + jr;
        gsH[h2][jj][lv]      = a0[jr];
        gsH[h2][jj][16 + lv] = a1[jr];
      }
    }
    __syncthreads();
    // phase 4: pointwise LSTM + F[t+1] h/c + score partials (one out/thread)
    {
      int b = tid & 31, r = tid >> 5;
      int ii = blk * 16 + r;
      float ig = gsA[(r) * 33 + b]      + gsH[0][r][b]      + gsH[1][r][b];
      float fg = gsA[(16 + r) * 33 + b] + gsH[0][16 + r][b] + gsH[1][16 + r][b];
      float gg = gsA[(32 + r) * 33 + b] + gsH[0][32 + r][b] + gsH[1][32 + r][b];
      float og = gsA[(48 + r) * 33 + b] + gsH[0][48 + r][b] + gsH[1][48 + r][b];
      float cv = cbc[b * H_ + ii];
      float cn = sigm(fg) * cv + sigm(ig) * tanhf(gg);
      float hn = sigm(og) * tanhf(cn);
      cbn[b * H_ + ii] = cn;
      Fall[((size_t)(t + 1) * 32 + b) * KIN + ii] = f2bf_rne(hn);
      Fall[((size_t)(t + 1) * 32 + b) * KIN + H_ + ii] = f2bf_rne(cn);
      scC[r * 32 + b] = hn * Wa[ii] + cn * Wa[512 + ii];
    }
    __syncthreads();
    if (tid < 32) {
      float s = 0.f;
      #pragma unroll
      for (int r = 0; r < 16; ++r) s += scC[r * 32 + tid];
      score_part[(t + 1) * 1024 + blk * 32 + tid] = s;
    }
  } else {
    // ---------- tf==0 slow correctness path: block owns batch b = blk ----
    const int b = blk;
    const float* hbc = hb + (t & 1) * B_ * H_;
    float* hbn = hb + ((t + 1) & 1) * B_ * H_;
    if (tid == 0) {
      float s = 0.f;
      for (int p = 0; p < 32; ++p) s += score_part[t * 1024 + p * 32 + b];
      score_t_[0] = s;
      token_sp = (t == 0) ? captions[b * T_]
                          : (int)(0xFFFFFFFFu - (unsigned)(argkey[b] & 0xFFFFFFFFull));
    }
    __syncthreads();
    if (tid < 64) {
      float s = tanhf(score_t_[0] + enc_score[b * 64 + tid] + ba[0]);
      float m = s;
      for (int o = 32; o; o >>= 1) m = fmaxf(m, __shfl_xor(m, o));
      float e = expf(s - m);
      float sum = e;
      for (int o = 32; o; o >>= 1) sum += __shfl_xor(sum, o);
      attn_s[tid] = e / sum;
    }
    __syncthreads();
    for (int i = tid; i < 512; i += 512) {
      xls[i] = hbc[b * H_ + i];
      xls[512 + i] = cbc[b * H_ + i];
      float a = 0.f;
      for (int k = 0; k < 64; ++k) a += attn_s[k] * enc[((size_t)b * 64 + k) * 512 + i];
      xls[1024 + i] = a;
      xls[1536 + i] = embt[(size_t)token_sp * 512 + i];
    }
    __syncthreads();
    for (int i = tid; i < 1024; i += 512)
      Fall[((size_t)t * 32 + b) * KIN + 1024 + i] = f2bf_rne(xls[1024 + i]);
    for (int j = tid; j < 2048; j += 512) {
      float a = b_ih[j] + b_hh[j];
      for (int e = 0; e < 1024; ++e) a += W_ih[(size_t)j * 1024 + e] * xls[1024 + e];
      for (int e = 0; e < 512; ++e)  a += W_hh[(size_t)j * 512 + e] * xls[e];
      gls[j] = a;
    }
    __syncthreads();
    {
      float sc = 0.f;
      for (int i = tid; i < 512; i += 512) {
        float ig = gls[i], fg = gls[512 + i], gg = gls[1024 + i], og = gls[1536 + i];
        float cv = xls[512 + i];
        float cn = sigm(fg) * cv + sigm(ig) * tanhf(gg);
        float hn = sigm(og) * tanhf(cn);
        hbn[b * H_ + i] = hn;
        cbn[b * H_ + i] = cn;
        Fall[((size_t)(t + 1) * 32 + b) * KIN + i] = f2bf_rne(hn);
        Fall[((size_t)(t + 1) * 32 + b) * KIN + H_ + i] = f2bf_rne(cn);
        sc += hn * Wa[i] + cn * Wa[512 + i];
      }
      scC[tid] = sc;
    }
    __syncthreads();
    if (tid == 0) {
      float s = 0.f;
      for (int q = 0; q < 512; ++q) s += scC[q];
      score_part[(t + 1) * 1024 + b] = s;
    }
    unsigned long long best = 0ull;
    for (int v = tid; v < V_; v += 512) {
      float d = bl[v];
      const float* wr = Wl + (size_t)v * KIN;
      for (int k = 0; k < KIN; ++k) d += wr[k] * xls[k];
      unsigned long long key = ((unsigned long long)ordf(d) << 32) | (0xFFFFFFFFu - (unsigned)v);
      if (key > best) best = key;
    }
    bred[tid] = best;
    __syncthreads();
    for (int o = 256; o; o >>= 1) {
      if (tid < o) bred[tid] = bred[tid] > bred[tid + o] ? bred[tid] : bred[tid + o];
      __syncthreads();
    }
    if (tid == 0) argkey[b] = bred[0];
  }
}

// ---- batched logits GEMM (proven v2, FROZEN): C[v][n] = Wl[v]·F[n] -------
#define GM   128
#define GNP  320
#define ABYTES 40960
#define BUFB  57344

__global__ __launch_bounds__(512, 2) void k_gemm(
    const unsigned short* __restrict__ wl_bf,
    const unsigned short* __restrict__ F,
    const float* __restrict__ bl,
    float* __restrict__ out) {
  extern __shared__ unsigned char lds[];
  const int tid = threadIdx.x;
  const int l = tid & 63, w = tid >> 6, lv = l & 15, lg = l >> 4;
  const int wm = w >> 2, wn = w & 3;
  const int m0 = blockIdx.x * GM;

  float blv[4];
  #pragma unroll
  for (int mi = 0; mi < 4; ++mi) blv[mi] = bl[m0 + wm * 64 + mi * 16 + lv];

  f32x4 acc[4][5];
  #pragma unroll
  for (int mi = 0; mi < 4; ++mi)
    #pragma unroll
    for (int ni = 0; ni < 5; ++ni) acc[mi][ni] = (f32x4){0.f, 0.f, 0.f, 0.f};

#define STAGE(c, buf) do {                                                    \
    int kb_ = ((c) & 31) * 64;                                                \
    int nb_ = ((c) >> 5) * GNP;                                               \
    unsigned char* bs_ = lds + (buf) * BUFB;                                  \
    _Pragma("unroll")                                                         \
    for (int i_ = 0; i_ < 5; ++i_) {                                          \
      int s_ = i_ * 512 + tid;                                                \
      int kq_ = s_ / 320, n_ = s_ - kq_ * 320;                                \
      gload16(F + (size_t)(nb_ + n_) * KIN + kb_ + kq_ * 8, bs_ + s_ * 16);   \
    }                                                                         \
    _Pragma("unroll")                                                         \
    for (int j_ = 0; j_ < 2; ++j_) {                                          \
      int s_ = j_ * 512 + tid;                                                \
      int kq_ = s_ >> 7, m_ = s_ & 127;                                       \
      gload16(wl_bf + (size_t)(m0 + m_) * KIN + kb_ + kq_ * 8,                \
              bs_ + ABYTES + s_ * 16);                                        \
    }                                                                         \
  } while (0)

#define COMPUTE(buf) do {                                                     \
    unsigned char* bs_ = lds + (buf) * BUFB;                                  \
    _Pragma("unroll")                                                         \
    for (int kk2_ = 0; kk2_ < 2; ++kk2_) {                                    \
      int kq_ = kk2_ * 4 + lg;                                                \
      bf16x8 bf_[4];                                                          \
      _Pragma("unroll")                                                       \
      for (int mi = 0; mi < 4; ++mi)                                          \
        bf_[mi] = *(const bf16x8*)(bs_ + ABYTES +                             \
                    (size_t)(kq_ * 128 + wm * 64 + mi * 16 + lv) * 16);       \
      _Pragma("unroll")                                                       \
      for (int ni = 0; ni < 5; ++ni) {                                        \
        bf16x8 af_ = *(const bf16x8*)(bs_ +                                   \
                    (size_t)(kq_ * 320 + wn * 80 + ni * 16 + lv) * 16);       \
        _Pragma("unroll")                                                     \
        for (int mi = 0; mi < 4; ++mi)                                        \
          acc[mi][ni] = __builtin_amdgcn_mfma_f32_16x16x32_bf16(              \
                          af_, bf_[mi], acc[mi][ni], 0, 0, 0);                \
      }                                                                       \
    }                                                                         \
  } while (0)

#define WRITEOUT(pass) do {                                                   \
    _Pragma("unroll")                                                         \
    for (int mi = 0; mi < 4; ++mi) {                                          \
      int v_ = m0 + wm * 64 + mi * 16 + lv;                                   \
      _Pragma("unroll")                                                       \
      for (int ni = 0; ni < 5; ++ni) {                                        \
        _Pragma("unroll")                                                     \
        for (int j_ = 0; j_ < 4; ++j_) {                                      \
          int n_ = (pass) * GNP + wn * 80 + ni * 16 + 4 * lg + j_;            \
          int tt_ = n_ >> 5, bb_ = n_ & 31;                                   \
          out[((size_t)bb_ * T_ + tt_) * V_ + v_] = acc[mi][ni][j_] + blv[mi];\
        }                                                                     \
      }                                                                       \
    }                                                                         \
  } while (0)

  STAGE(0, 0);
  int cur = 0;
  for (int c = 0; c < 64; ++c) {
    __syncthreads();
    if (c < 63) STAGE(c + 1, cur ^ 1);
    COMPUTE(cur);
    if (c == 31) {
      WRITEOUT(0);
      #pragma unroll
      for (int mi = 0; mi < 4; ++mi)
        #pragma unroll
        for (int ni = 0; ni < 5; ++ni) acc[mi][ni] = (f32x4){0.f, 0.f, 0.f, 0.f};
    }
    cur ^= 1;
  }
  WRITEOUT(1);
#undef STAGE
#undef COMPUTE
#undef WRITEOUT
}

// ---- final: in-place log_softmax -----------------------------------------
__global__ void k_lsm(float* __restrict__ out) {
  float4* p = (float4*)(out + (size_t)blockIdx.x * V_);
  int tid = threadIdx.x;
  __shared__ float smax[4], ssum[4];
  const int N4 = V_ / 4;
  float m = -1e30f, s = 0.f;
  for (int i = tid; i < N4; i += 256) {
    float4 v = p[i];
    float lm = fmaxf(fmaxf(v.x, v.y), fmaxf(v.z, v.w));
    if (lm > m) { s *= expf(m - lm); m = lm; }
    s += expf(v.x - m) + expf(v.y - m) + expf(v.z - m) + expf(v.w - m);
  }
  for (int o = 32; o; o >>= 1) {
    float m2 = __shfl_xor(m, o), s2 = __shfl_xor(s, o);
    float mn = fmaxf(m, m2);
    s = s * expf(m - mn) + s2 * expf(m2 - mn);
    m = mn;
  }
  if ((tid & 63) == 0) { smax[tid >> 6] = m; ssum[tid >> 6] = s; }
  __syncthreads();
  float mg = fmaxf(fmaxf(smax[0], smax[1]), fmaxf(smax[2], smax[3]));
  float sg = ssum[0] * expf(smax[0] - mg) + ssum[1] * expf(smax[1] - mg)
           + ssum[2] * expf(smax[2] - mg) + ssum[3] * expf(smax[3] - mg);
  float lse = mg + logf(sg);
  for (int i = tid; i < N4; i += 256) {
    float4 v = p[i];
    v.x -= lse; v.y -= lse; v.z -= lse; v.w -= lse;
    p[i] = v;
  }
}

extern "C" void kernel_launch(void* const* d_in, const int* in_sizes, int n_in,
                              void* d_out, int out_size, void* d_ws, size_t ws_size,
                              hipStream_t stream) {
  const float* enc      = (const float*)d_in[0];
  const float* embt     = (const float*)d_in[1];
  const float* Wa       = (const float*)d_in[2];
  const float* ba       = (const float*)d_in[3];
  const float* W_ih     = (const float*)d_in[4];
  const float* W_hh     = (const float*)d_in[5];
  const float* b_ih     = (const float*)d_in[6];
  const float* b_hh     = (const float*)d_in[7];
  const float* Wl       = (const float*)d_in[8];
  const float* bl       = (const float*)d_in[9];
  const int*   captions = (const int*)d_in[10];
  const int*   tf       = (const int*)d_in[11];
  float* out = (float*)d_out;
  char*  ws  = (char*)d_ws;

  size_t off = 0;
  unsigned short* Fall = (unsigned short*)(ws + off); off += (size_t)(T_ + 1) * B_ * KIN * 2;
  float* hb            = (float*)(ws + off);          off += (size_t)2 * B_ * H_ * 4;
  float* cb            = (float*)(ws + off);          off += (size_t)2 * B_ * H_ * 4;
  float* enc_score     = (float*)(ws + off);          off += (size_t)B_ * K_ * 4;
  float* score_part    = (float*)(ws + off);          off += (size_t)(T_ + 1) * 1024 * 4;
  unsigned long long* argkey = (unsigned long long*)(ws + off); off += 256;
  float* bias_arr      = (float*)(ws + off);          off += 2048 * 4;
  off = (off + 1023) & ~(size_t)1023;
  unsigned short* wih_hi = (unsigned short*)(ws + off); off += (size_t)2048 * 1024 * 2;
  unsigned short* wih_lo = (unsigned short*)(ws + off); off += (size_t)2048 * 1024 * 2;
  unsigned short* whh_hi = (unsigned short*)(ws + off); off += (size_t)NBLK * 64 * 512 * 2;
  unsigned short* whh_lo = (unsigned short*)(ws + off); off += (size_t)NBLK * 64 * 512 * 2;
  unsigned short* enc_bf = (unsigned short*)(ws + off); off += (size_t)2048 * 512 * 2;
  unsigned short* emb_bf = (unsigned short*)(ws + off); off += (size_t)640 * 512 * 2;
  float* Genc          = (float*)(ws + off);          off += (size_t)NBLK * 2048 * 64 * 4;
  float* Gemb          = (float*)(ws + off);          off += (size_t)NBLK * 640 * 64 * 4;
  unsigned short* wl_bf = (unsigned short*)(ws + off); off += (size_t)V_ * KIN * 2;

  k_prep<<<512, 256, 0, stream>>>(W_ih, W_hh, b_ih, b_hh, enc, embt, Wa, captions,
                                  wih_hi, wih_lo, whh_hi, whh_lo, enc_bf, emb_bf,
                                  bias_arr, score_part, argkey, hb, cb, enc_score,
                                  Fall);
  k_gpre<<<dim3(NBLK, 21), 256, 0, stream>>>(wih_hi, wih_lo, enc_bf, emb_bf,
                                             Genc, Gemb);

  for (int t = 0; t < T_; ++t) {
    k_step<<<NBLK + NCONV, 512, 0, stream>>>(
        enc, embt, Wa, ba, W_ih, W_hh, b_ih, b_hh,
        Wl, bl, captions, tf, Genc, Gemb,
        whh_hi, whh_lo, bias_arr, enc_score,
        score_part, Fall, hb, cb, argkey, wl_bf, t);
  }
  k_gemm<<<V_ / GM, 512, 2 * BUFB, stream>>>(wl_bf, Fall, bl, out);
  k_lsm<<<B_ * T_, 256, 0, stream>>>(out);
}

// Round 19
// 723.594 us; speedup vs baseline: 1.2808x; 1.0259x over previous
//
#include <hip/hip_runtime.h>
#include <hip/hip_bf16.h>
#include <stdint.h>

#define B_   32
#define K_   64
#define E_   512
#define H_   512
#define M_   512
#define T_   20
#define V_   32000
#define KIN  2048   // 2H + E + M
#define NBLK 32     // chain blocks / j-groups
#define NCONV 224   // conv helper blocks in k_step

typedef __bf16 bf16x8 __attribute__((ext_vector_type(8)));
typedef float  f32x4  __attribute__((ext_vector_type(4)));

__device__ inline unsigned short f2bf_rne(float f) {
  union { float f; unsigned u; } v; v.f = f;
  unsigned r = v.u + 0x7FFFu + ((v.u >> 16) & 1u);
  return (unsigned short)(r >> 16);
}
__device__ inline float bf2f(unsigned short s) {
  union { unsigned u; float f; } v; v.u = ((unsigned)s) << 16;
  return v.f;
}
__device__ inline float sigm(float x) { return 1.f / (1.f + expf(-x)); }
__device__ inline unsigned ordf(float f) {
  unsigned u = __float_as_uint(f);
  return (u & 0x80000000u) ? ~u : (u | 0x80000000u);
}
__device__ __forceinline__ void gload16(const void* g, void* l) {
  __builtin_amdgcn_global_load_lds(
      (const __attribute__((address_space(1))) void*)g,
      (__attribute__((address_space(3))) void*)l, 16, 0, 0);
}

// j-group mapping: block blk owns jj in [0,64): global j = (jj>>4)*512 + blk*16 + (jj&15)

// ---- prep (+init merged): weight splits, enc/emb bf16, F emb cols, bias,
//      zeros, h0/c0, F[0] h/c, enc_score, score_part[0] --------------------
__global__ void k_prep(const float* __restrict__ W_ih, const float* __restrict__ W_hh,
                       const float* __restrict__ b_ih, const float* __restrict__ b_hh,
                       const float* __restrict__ enc, const float* __restrict__ embt,
                       const float* __restrict__ Wa, const int* __restrict__ captions,
                       unsigned short* __restrict__ wih_hi, unsigned short* __restrict__ wih_lo,
                       unsigned short* __restrict__ whh_hi, unsigned short* __restrict__ whh_lo,
                       unsigned short* __restrict__ enc_bf, unsigned short* __restrict__ emb_bf,
                       float* __restrict__ bias_arr, float* __restrict__ score_part,
                       unsigned long long* __restrict__ argkey,
                       float* __restrict__ hb, float* __restrict__ cb,
                       float* __restrict__ enc_score,
                       unsigned short* __restrict__ Fall) {
  int tid0 = blockIdx.x * 256 + threadIdx.x;
  int NT = gridDim.x * 256;
  for (int i = tid0; i < 2048 * 1024; i += NT) {            // W_ih hi/lo
    float f = W_ih[i];
    unsigned short h = f2bf_rne(f);
    wih_hi[i] = h; wih_lo[i] = f2bf_rne(f - bf2f(h));
  }
  for (int i = tid0; i < NBLK * 64 * 512; i += NT) {        // W_hh rearranged [blk][jj][512]
    int e = i & 511, jj = (i >> 9) & 63, blk = i >> 15;
    int jg = (jj >> 4) * 512 + blk * 16 + (jj & 15);
    float f = W_hh[jg * 512 + e];
    unsigned short h = f2bf_rne(f);
    whh_hi[i] = h; whh_lo[i] = f2bf_rne(f - bf2f(h));
  }
  for (int i = tid0; i < 2048 * 512; i += NT) enc_bf[i] = f2bf_rne(enc[i]);
  for (int i = tid0; i < 640 * 512; i += NT) {              // emb rows + F emb cols (tf=1)
    int n = i >> 9, m = i & 511;
    int t = n >> 5, b = n & 31;
    int tok = captions[b * T_ + (t > 0 ? t - 1 : 0)];
    unsigned short ev = f2bf_rne(embt[(size_t)tok * 512 + m]);
    emb_bf[i] = ev;
    Fall[(size_t)n * KIN + 1536 + m] = ev;
  }
  for (int i = tid0; i < 2048; i += NT) {                   // bias [blk][jj]
    int blk = i >> 6, jj = i & 63;
    int jg = (jj >> 4) * 512 + blk * 16 + (jj & 15);
    bias_arr[i] = b_ih[jg] + b_hh[jg];
  }
  for (int i = tid0; i < (T_ + 1) * 1024; i += NT)
    if (i >= 32) score_part[i] = 0.f;                       // init owns [0,32)
  for (int i = tid0; i < 32; i += NT) argkey[i] = 0ull;

  // ---- merged k_init (blocks 0..63; same idx mapping as before) ----------
  if (blockIdx.x < 64) {
    int idx = blockIdx.x * 256 + threadIdx.x;
    int b = idx >> 9, i = idx & 511;
    float v = enc[(size_t)b * K_ * E_ + (size_t)(K_ - 1) * E_ + i];
    hb[b * H_ + i] = v;
    cb[b * H_ + i] = v;
    unsigned short bv = f2bf_rne(v);
    Fall[b * KIN + i] = bv;
    Fall[b * KIN + H_ + i] = bv;
    if (idx < B_ * K_) {
      int bb = idx >> 6, k = idx & 63;
      const float4* e4  = (const float4*)(enc + ((size_t)bb * K_ + k) * E_);
      const float4* wa4 = (const float4*)(Wa + 2 * H_);
      float acc = 0.f;
      #pragma unroll 4
      for (int q = 0; q < E_ / 4; ++q) {
        float4 a = e4[q], w = wa4[q];
        acc += a.x * w.x + a.y * w.y + a.z * w.z + a.w * w.w;
      }
      enc_score[idx] = acc;
    }
    if (idx < 2048) {   // score_part[0][0][b] = dot([h0,c0], Wa[:1024]), h0=c0
      int bb = idx >> 6, l = idx & 63;
      float s = 0.f;
      #pragma unroll
      for (int q = 0; q < 8; ++q) {
        int ii = l * 8 + q;
        float hv = enc[(size_t)bb * K_ * E_ + (size_t)(K_ - 1) * E_ + ii];
        s += hv * (Wa[ii] + Wa[512 + ii]);
      }
      for (int o = 32; o; o >>= 1) s += __shfl_down(s, o);
      if (l == 0) score_part[bb] = s;
    }
  }
}

// ---- precompute G = (W_ih hi/lo) @ B^T -> bf16, enc+emb via blockIdx.y ---
// y<16: enc (N=2048, koff=0, Genc); y>=16: emb (N=640, koff=512, Gemb).
__global__ __launch_bounds__(256) void k_gpre(
    const unsigned short* __restrict__ whi, const unsigned short* __restrict__ wlo,
    const unsigned short* __restrict__ enc_bf, const unsigned short* __restrict__ emb_bf,
    unsigned short* __restrict__ Genc, unsigned short* __restrict__ Gemb) {
  int blk = blockIdx.x;
  int nt = blockIdx.y;
  const unsigned short* Bm;
  unsigned short* outp;
  int N, koff;
  if (nt < 16) { Bm = enc_bf; outp = Genc; N = 2048; koff = 0; }
  else         { Bm = emb_bf; outp = Gemb; N = 640;  koff = 512; nt -= 16; }
  int tid = threadIdx.x;
  int l = tid & 63, w = tid >> 6, lv = l & 15, lg = l >> 4;
  const int n0 = nt * 128 + w * 32;

  f32x4 acc[4][2];
  #pragma unroll
  for (int jf = 0; jf < 4; ++jf)
    #pragma unroll
    for (int nf = 0; nf < 2; ++nf) acc[jf][nf] = (f32x4){0.f, 0.f, 0.f, 0.f};

  #pragma unroll 4
  for (int kk = 0; kk < 16; ++kk) {
    bf16x8 bfr[2];
    #pragma unroll
    for (int nf = 0; nf < 2; ++nf)
      bfr[nf] = *(const bf16x8*)(Bm + (size_t)(n0 + nf * 16 + lv) * 512 + kk * 32 + lg * 8);
    #pragma unroll
    for (int jf = 0; jf < 4; ++jf) {
      int jg = jf * 512 + blk * 16 + lv;
      bf16x8 ahi = *(const bf16x8*)(whi + (size_t)jg * 1024 + koff + kk * 32 + lg * 8);
      bf16x8 alo = *(const bf16x8*)(wlo + (size_t)jg * 1024 + koff + kk * 32 + lg * 8);
      #pragma unroll
      for (int nf = 0; nf < 2; ++nf) {
        acc[jf][nf] = __builtin_amdgcn_mfma_f32_16x16x32_bf16(ahi, bfr[nf], acc[jf][nf], 0, 0, 0);
        acc[jf][nf] = __builtin_amdgcn_mfma_f32_16x16x32_bf16(alo, bfr[nf], acc[jf][nf], 0, 0, 0);
      }
    }
  }
  #pragma unroll
  for (int jf = 0; jf < 4; ++jf)
    #pragma unroll
    for (int nf = 0; nf < 2; ++nf)
      #pragma unroll
      for (int jr = 0; jr < 4; ++jr) {
        int n = n0 + nf * 16 + lv;
        int jj = jf * 16 + 4 * lg + jr;
        outp[((size_t)blk * N + n) * 64 + jj] = f2bf_rne(acc[jf][nf][jr]);
      }
}

// ---- per step: blocks 0-31 chain; blocks 32-255 convert Wl slice t -------
__global__ __launch_bounds__(512) void k_step(
    const float* __restrict__ enc, const float* __restrict__ embt,
    const float* __restrict__ Wa, const float* __restrict__ ba,
    const float* __restrict__ W_ih, const float* __restrict__ W_hh,
    const float* __restrict__ b_ih, const float* __restrict__ b_hh,
    const float* __restrict__ Wl, const float* __restrict__ bl,
    const int* __restrict__ captions, const int* __restrict__ tf_flag,
    const unsigned short* __restrict__ Genc, const unsigned short* __restrict__ Gemb,
    const unsigned short* __restrict__ whh_hi, const unsigned short* __restrict__ whh_lo,
    const float* __restrict__ bias_arr, const float* __restrict__ enc_score,
    float* __restrict__ score_part, unsigned short* __restrict__ Fall,
    float* __restrict__ hb, float* __restrict__ cb,
    unsigned long long* __restrict__ argkey, unsigned short* __restrict__ wl_bf,
    int t) {
  const int blk = blockIdx.x;
  const int tid = threadIdx.x;

  if (blk >= NBLK) {
    // ---- convert Wl slice t (1/20 of the matrix) -------------------------
    const int NC = V_ * KIN / 4;              // 16,384,000 f32x4's
    const int per = (NC + T_ - 1) / T_;       // 819,200
    int lo = t * per;
    int hi = lo + per; if (hi > NC) hi = NC;
    for (int i = lo + (blk - NBLK) * 512 + tid; i < hi; i += NCONV * 512) {
      f32x4 v = __builtin_nontemporal_load((const f32x4*)Wl + i);
      ushort4 o;
      o.x = f2bf_rne(v.x); o.y = f2bf_rne(v.y); o.z = f2bf_rne(v.z); o.w = f2bf_rne(v.w);
      ((ushort4*)wl_bf)[i] = o;
    }
    return;
  }

  __shared__ float attn_s[B_ * K_];
  __shared__ float gsA[64 * 33];
  __shared__ float gsH[2][64][32];
  __shared__ float scC[512];
  __shared__ float score_t_[32];
  __shared__ int   token_sp;
  __shared__ float xls[KIN];
  __shared__ float gls[2048];
  __shared__ unsigned long long bred[512];
  const float* cbc = cb + (t & 1) * B_ * H_;
  float* cbn = cb + ((t + 1) & 1) * B_ * H_;

  if (tf_flag[0]) {
    // phase 0: assemble scores (deterministic per-slot partials)
    if (tid < 32) {
      float s = 0.f;
      #pragma unroll 8
      for (int p = 0; p < 32; ++p) s += score_part[t * 1024 + p * 32 + tid];
      score_t_[tid] = s;
    }
    __syncthreads();
    // phase 1: softmax (8 waves x 4 batches; lanes = k)
    {
      int w = tid >> 6, l = tid & 63;
      float ba0 = ba[0];
      #pragma unroll
      for (int bb = 0; bb < 4; ++bb) {
        int b = w * 4 + bb;
        float s = tanhf(score_t_[b] + enc_score[b * 64 + l] + ba0);
        float m = s;
        for (int o = 32; o; o >>= 1) m = fmaxf(m, __shfl_xor(m, o));
        float e = expf(s - m);
        float sum = e;
        for (int o = 32; o; o >>= 1) sum += __shfl_xor(sum, o);
        attn_s[b * 64 + l] = e / sum;
      }
    }
    __syncthreads();
    // phase 2: gsA[jj][b] = sum_k attn*Genc + Gemb + bias (Genc/Gemb bf16;
    // per-output k-order identical to r18 -> only operand rounding changed)
    {
      int b = tid >> 4, jj4 = tid & 15;
      const unsigned short* gp = Genc + ((size_t)blk * 2048 + b * 64) * 64 + jj4 * 4;
      const float* ap = attn_s + b * 64;
      f32x4 s = {0.f, 0.f, 0.f, 0.f};
      #pragma unroll 8
      for (int k = 0; k < 64; ++k) {
        float a = ap[k];
        ushort4 g = *(const ushort4*)(gp + (size_t)k * 64);
        s[0] += a * bf2f(g.x); s[1] += a * bf2f(g.y);
        s[2] += a * bf2f(g.z); s[3] += a * bf2f(g.w);
      }
      ushort4 e = *(const ushort4*)(Gemb + ((size_t)blk * 640 + t * 32 + b) * 64 + jj4 * 4);
      const f32x4* B4 = (const f32x4*)bias_arr;
      f32x4 bb = B4[blk * 16 + jj4];
      float ef[4] = {bf2f(e.x), bf2f(e.y), bf2f(e.z), bf2f(e.w)};
      #pragma unroll
      for (int q = 0; q < 4; ++q) {
        float v = s[q] + (ef[q] + bb[q]);
        gsA[(jj4 * 4 + q) * 33 + b] = v;
      }
    }
    // phase 2.5: context fill for batch b = blk (bit-exact k_fill loop)
    {
      const float* aw = attn_s + blk * 64;
      int e = tid;
      if (e < 512) {
        float a = 0.f;
        #pragma unroll 8
        for (int k = 0; k < 64; ++k) a += aw[k] * enc[((size_t)blk * 64 + k) * 512 + e];
        Fall[((size_t)t * 32 + blk) * KIN + 1024 + e] = f2bf_rne(a);
      }
    }
    // phase 3: (W_hh hi/lo) @ h_t, K split across wave pairs (r5 pattern)
    {
      int w = tid >> 6, l = tid & 63, lv = l & 15, lg = l >> 4;
      int g = w & 3, h2 = w >> 2;
      const unsigned short* ah = whh_hi + ((size_t)blk * 64 + g * 16 + lv) * 512 + h2 * 256 + lg * 8;
      const unsigned short* al = whh_lo + ((size_t)blk * 64 + g * 16 + lv) * 512 + h2 * 256 + lg * 8;
      const unsigned short* f0 = Fall + ((size_t)t * 32 + lv) * KIN + h2 * 256 + lg * 8;
      const unsigned short* f1 = Fall + ((size_t)t * 32 + 16 + lv) * KIN + h2 * 256 + lg * 8;
      f32x4 a0 = {0.f, 0.f, 0.f, 0.f};
      f32x4 a1 = {0.f, 0.f, 0.f, 0.f};
      #pragma unroll 8
      for (int kk = 0; kk < 8; ++kk) {
        bf16x8 hi = *(const bf16x8*)(ah + kk * 32);
        bf16x8 lo = *(const bf16x8*)(al + kk * 32);
        bf16x8 b0 = *(const bf16x8*)(f0 + kk * 32);
        bf16x8 b1 = *(const bf16x8*)(f1 + kk * 32);
        a0 = __builtin_amdgcn_mfma_f32_16x16x32_bf16(hi, b0, a0, 0, 0, 0);
        a0 = __builtin_amdgcn_mfma_f32_16x16x32_bf16(lo, b0, a0, 0, 0, 0);
        a1 = __builtin_amdgcn_mfma_f32_16x16x32_bf16(hi, b1, a1, 0, 0, 0);
        a1 = __builtin_amdgcn_mfma_f32_16x16x32_bf16(lo, b1, a1, 0, 0, 0);
      }
      #pragma unroll
      for (int jr = 0; jr < 4; ++jr) {
        int jj = g * 16 + 4 * lg + jr;
        gsH[h2][jj][lv]      = a0[jr];
        gsH[h2][jj][16 + lv] = a1[jr];
      }
    }
    __syncthreads();
    // phase 4: pointwise LSTM + F[t+1] h/c + score partials (one out/thread)
    {
      int b = tid & 31, r = tid >> 5;
      int ii = blk * 16 + r;
      float ig = gsA[(r) * 33 + b]      + gsH[0][r][b]      + gsH[1][r][b];
      float fg = gsA[(16 + r) * 33 + b] + gsH[0][16 + r][b] + gsH[1][16 + r][b];
      float gg = gsA[(32 + r) * 33 + b] + gsH[0][32 + r][b] + gsH[1][32 + r][b];
      float og = gsA[(48 + r) * 33 + b] + gsH[0][48 + r][b] + gsH[1][48 + r][b];
      float cv = cbc[b * H_ + ii];
      float cn = sigm(fg) * cv + sigm(ig) * tanhf(gg);
      float hn = sigm(og) * tanhf(cn);
      cbn[b * H_ + ii] = cn;
      Fall[((size_t)(t + 1) * 32 + b) * KIN + ii] = f2bf_rne(hn);
      Fall[((size_t)(t + 1) * 32 + b) * KIN + H_ + ii] = f2bf_rne(cn);
      scC[r * 32 + b] = hn * Wa[ii] + cn * Wa[512 + ii];
    }
    __syncthreads();
    if (tid < 32) {
      float s = 0.f;
      #pragma unroll
      for (int r = 0; r < 16; ++r) s += scC[r * 32 + tid];
      score_part[(t + 1) * 1024 + blk * 32 + tid] = s;
    }
  } else {
    // ---------- tf==0 slow correctness path: block owns batch b = blk ----
    const int b = blk;
    const float* hbc = hb + (t & 1) * B_ * H_;
    float* hbn = hb + ((t + 1) & 1) * B_ * H_;
    if (tid == 0) {
      float s = 0.f;
      for (int p = 0; p < 32; ++p) s += score_part[t * 1024 + p * 32 + b];
      score_t_[0] = s;
      token_sp = (t == 0) ? captions[b * T_]
                          : (int)(0xFFFFFFFFu - (unsigned)(argkey[b] & 0xFFFFFFFFull));
    }
    __syncthreads();
    if (tid < 64) {
      float s = tanhf(score_t_[0] + enc_score[b * 64 + tid] + ba[0]);
      float m = s;
      for (int o = 32; o; o >>= 1) m = fmaxf(m, __shfl_xor(m, o));
      float e = expf(s - m);
      float sum = e;
      for (int o = 32; o; o >>= 1) sum += __shfl_xor(sum, o);
      attn_s[tid] = e / sum;
    }
    __syncthreads();
    for (int i = tid; i < 512; i += 512) {
      xls[i] = hbc[b * H_ + i];
      xls[512 + i] = cbc[b * H_ + i];
      float a = 0.f;
      for (int k = 0; k < 64; ++k) a += attn_s[k] * enc[((size_t)b * 64 + k) * 512 + i];
      xls[1024 + i] = a;
      xls[1536 + i] = embt[(size_t)token_sp * 512 + i];
    }
    __syncthreads();
    for (int i = tid; i < 1024; i += 512)
      Fall[((size_t)t * 32 + b) * KIN + 1024 + i] = f2bf_rne(xls[1024 + i]);
    for (int j = tid; j < 2048; j += 512) {
      float a = b_ih[j] + b_hh[j];
      for (int e = 0; e < 1024; ++e) a += W_ih[(size_t)j * 1024 + e] * xls[1024 + e];
      for (int e = 0; e < 512; ++e)  a += W_hh[(size_t)j * 512 + e] * xls[e];
      gls[j] = a;
    }
    __syncthreads();
    {
      float sc = 0.f;
      for (int i = tid; i < 512; i += 512) {
        float ig = gls[i], fg = gls[512 + i], gg = gls[1024 + i], og = gls[1536 + i];
        float cv = xls[512 + i];
        float cn = sigm(fg) * cv + sigm(ig) * tanhf(gg);
        float hn = sigm(og) * tanhf(cn);
        hbn[b * H_ + i] = hn;
        cbn[b * H_ + i] = cn;
        Fall[((size_t)(t + 1) * 32 + b) * KIN + i] = f2bf_rne(hn);
        Fall[((size_t)(t + 1) * 32 + b) * KIN + H_ + i] = f2bf_rne(cn);
        sc += hn * Wa[i] + cn * Wa[512 + i];
      }
      scC[tid] = sc;
    }
    __syncthreads();
    if (tid == 0) {
      float s = 0.f;
      for (int q = 0; q < 512; ++q) s += scC[q];
      score_part[(t + 1) * 1024 + b] = s;
    }
    unsigned long long best = 0ull;
    for (int v = tid; v < V_; v += 512) {
      float d = bl[v];
      const float* wr = Wl + (size_t)v * KIN;
      for (int k = 0; k < KIN; ++k) d += wr[k] * xls[k];
      unsigned long long key = ((unsigned long long)ordf(d) << 32) | (0xFFFFFFFFu - (unsigned)v);
      if (key > best) best = key;
    }
    bred[tid] = best;
    __syncthreads();
    for (int o = 256; o; o >>= 1) {
      if (tid < o) bred[tid] = bred[tid] > bred[tid + o] ? bred[tid] : bred[tid + o];
      __syncthreads();
    }
    if (tid == 0) argkey[b] = bred[0];
  }
}

// ---- batched logits GEMM (proven v2, FROZEN): C[v][n] = Wl[v]·F[n] -------
#define GM   128
#define GNP  320
#define ABYTES 40960
#define BUFB  57344

__global__ __launch_bounds__(512, 2) void k_gemm(
    const unsigned short* __restrict__ wl_bf,
    const unsigned short* __restrict__ F,
    const float* __restrict__ bl,
    float* __restrict__ out) {
  extern __shared__ unsigned char lds[];
  const int tid = threadIdx.x;
  const int l = tid & 63, w = tid >> 6, lv = l & 15, lg = l >> 4;
  const int wm = w >> 2, wn = w & 3;
  const int m0 = blockIdx.x * GM;

  float blv[4];
  #pragma unroll
  for (int mi = 0; mi < 4; ++mi) blv[mi] = bl[m0 + wm * 64 + mi * 16 + lv];

  f32x4 acc[4][5];
  #pragma unroll
  for (int mi = 0; mi < 4; ++mi)
    #pragma unroll
    for (int ni = 0; ni < 5; ++ni) acc[mi][ni] = (f32x4){0.f, 0.f, 0.f, 0.f};

#define STAGE(c, buf) do {                                                    \
    int kb_ = ((c) & 31) * 64;                                                \
    int nb_ = ((c) >> 5) * GNP;                                               \
    unsigned char* bs_ = lds + (buf) * BUFB;                                  \
    _Pragma("unroll")                                                         \
    for (int i_ = 0; i_ < 5; ++i_) {                                          \
      int s_ = i_ * 512 + tid;                                                \
      int kq_ = s_ / 320, n_ = s_ - kq_ * 320;                                \
      gload16(F + (size_t)(nb_ + n_) * KIN + kb_ + kq_ * 8, bs_ + s_ * 16);   \
    }                                                                         \
    _Pragma("unroll")                                                         \
    for (int j_ = 0; j_ < 2; ++j_) {                                          \
      int s_ = j_ * 512 + tid;                                                \
      int kq_ = s_ >> 7, m_ = s_ & 127;                                       \
      gload16(wl_bf + (size_t)(m0 + m_) * KIN + kb_ + kq_ * 8,                \
              bs_ + ABYTES + s_ * 16);                                        \
    }                                                                         \
  } while (0)

#define COMPUTE(buf) do {                                                     \
    unsigned char* bs_ = lds + (buf) * BUFB;                                  \
    _Pragma("unroll")                                                         \
    for (int kk2_ = 0; kk2_ < 2; ++kk2_) {                                    \
      int kq_ = kk2_ * 4 + lg;                                                \
      bf16x8 bf_[4];                                                          \
      _Pragma("unroll")                                                       \
      for (int mi = 0; mi < 4; ++mi)                                          \
        bf_[mi] = *(const bf16x8*)(bs_ + ABYTES +                             \
                    (size_t)(kq_ * 128 + wm * 64 + mi * 16 + lv) * 16);       \
      _Pragma("unroll")                                                       \
      for (int ni = 0; ni < 5; ++ni) {                                        \
        bf16x8 af_ = *(const bf16x8*)(bs_ +                                   \
                    (size_t)(kq_ * 320 + wn * 80 + ni * 16 + lv) * 16);       \
        _Pragma("unroll")                                                     \
        for (int mi = 0; mi < 4; ++mi)                                        \
          acc[mi][ni] = __builtin_amdgcn_mfma_f32_16x16x32_bf16(              \
                          af_, bf_[mi], acc[mi][ni], 0, 0, 0);                \
      }                                                                       \
    }                                                                         \
  } while (0)

#define WRITEOUT(pass) do {                                                   \
    _Pragma("unroll")                                                         \
    for (int mi = 0; mi < 4; ++mi) {                                          \
      int v_ = m0 + wm * 64 + mi * 16 + lv;                                   \
      _Pragma("unroll")                                                       \
      for (int ni = 0; ni < 5; ++ni) {                                        \
        _Pragma("unroll")                                                     \
        for (int j_ = 0; j_ < 4; ++j_) {                                      \
          int n_ = (pass) * GNP + wn * 80 + ni * 16 + 4 * lg + j_;            \
          int tt_ = n_ >> 5, bb_ = n_ & 31;                                   \
          out[((size_t)bb_ * T_ + tt_) * V_ + v_] = acc[mi][ni][j_] + blv[mi];\
        }                                                                     \
      }                                                                       \
    }                                                                         \
  } while (0)

  STAGE(0, 0);
  int cur = 0;
  for (int c = 0; c < 64; ++c) {
    __syncthreads();
    if (c < 63) STAGE(c + 1, cur ^ 1);
    COMPUTE(cur);
    if (c == 31) {
      WRITEOUT(0);
      #pragma unroll
      for (int mi = 0; mi < 4; ++mi)
        #pragma unroll
        for (int ni = 0; ni < 5; ++ni) acc[mi][ni] = (f32x4){0.f, 0.f, 0.f, 0.f};
    }
    cur ^= 1;
  }
  WRITEOUT(1);
#undef STAGE
#undef COMPUTE
#undef WRITEOUT
}

// ---- final: in-place log_softmax -----------------------------------------
__global__ void k_lsm(float* __restrict__ out) {
  float4* p = (float4*)(out + (size_t)blockIdx.x * V_);
  int tid = threadIdx.x;
  __shared__ float smax[4], ssum[4];
  const int N4 = V_ / 4;
  float m = -1e30f, s = 0.f;
  for (int i = tid; i < N4; i += 256) {
    float4 v = p[i];
    float lm = fmaxf(fmaxf(v.x, v.y), fmaxf(v.z, v.w));
    if (lm > m) { s *= expf(m - lm); m = lm; }
    s += expf(v.x - m) + expf(v.y - m) + expf(v.z - m) + expf(v.w - m);
  }
  for (int o = 32; o; o >>= 1) {
    float m2 = __shfl_xor(m, o), s2 = __shfl_xor(s, o);
    float mn = fmaxf(m, m2);
    s = s * expf(m - mn) + s2 * expf(m2 - mn);
    m = mn;
  }
  if ((tid & 63) == 0) { smax[tid >> 6] = m; ssum[tid >> 6] = s; }
  __syncthreads();
  float mg = fmaxf(fmaxf(smax[0], smax[1]), fmaxf(smax[2], smax[3]));
  float sg = ssum[0] * expf(smax[0] - mg) + ssum[1] * expf(smax[1] - mg)
           + ssum[2] * expf(smax[2] - mg) + ssum[3] * expf(smax[3] - mg);
  float lse = mg + logf(sg);
  for (int i = tid; i < N4; i += 256) {
    float4 v = p[i];
    v.x -= lse; v.y -= lse; v.z -= lse; v.w -= lse;
    p[i] = v;
  }
}

extern "C" void kernel_launch(void* const* d_in, const int* in_sizes, int n_in,
                              void* d_out, int out_size, void* d_ws, size_t ws_size,
                              hipStream_t stream) {
  const float* enc      = (const float*)d_in[0];
  const float* embt     = (const float*)d_in[1];
  const float* Wa       = (const float*)d_in[2];
  const float* ba       = (const float*)d_in[3];
  const float* W_ih     = (const float*)d_in[4];
  const float* W_hh     = (const float*)d_in[5];
  const float* b_ih     = (const float*)d_in[6];
  const float* b_hh     = (const float*)d_in[7];
  const float* Wl       = (const float*)d_in[8];
  const float* bl       = (const float*)d_in[9];
  const int*   captions = (const int*)d_in[10];
  const int*   tf       = (const int*)d_in[11];
  float* out = (float*)d_out;
  char*  ws  = (char*)d_ws;

  size_t off = 0;
  unsigned short* Fall = (unsigned short*)(ws + off); off += (size_t)(T_ + 1) * B_ * KIN * 2;
  float* hb            = (float*)(ws + off);          off += (size_t)2 * B_ * H_ * 4;
  float* cb            = (float*)(ws + off);          off += (size_t)2 * B_ * H_ * 4;
  float* enc_score     = (float*)(ws + off);          off += (size_t)B_ * K_ * 4;
  float* score_part    = (float*)(ws + off);          off += (size_t)(T_ + 1) * 1024 * 4;
  unsigned long long* argkey = (unsigned long long*)(ws + off); off += 256;
  float* bias_arr      = (float*)(ws + off);          off += 2048 * 4;
  off = (off + 1023) & ~(size_t)1023;
  unsigned short* wih_hi = (unsigned short*)(ws + off); off += (size_t)2048 * 1024 * 2;
  unsigned short* wih_lo = (unsigned short*)(ws + off); off += (size_t)2048 * 1024 * 2;
  unsigned short* whh_hi = (unsigned short*)(ws + off); off += (size_t)NBLK * 64 * 512 * 2;
  unsigned short* whh_lo = (unsigned short*)(ws + off); off += (size_t)NBLK * 64 * 512 * 2;
  unsigned short* enc_bf = (unsigned short*)(ws + off); off += (size_t)2048 * 512 * 2;
  unsigned short* emb_bf = (unsigned short*)(ws + off); off += (size_t)640 * 512 * 2;
  unsigned short* Genc = (unsigned short*)(ws + off); off += (size_t)NBLK * 2048 * 64 * 2;
  unsigned short* Gemb = (unsigned short*)(ws + off); off += (size_t)NBLK * 640 * 64 * 2;
  unsigned short* wl_bf = (unsigned short*)(ws + off); off += (size_t)V_ * KIN * 2;

  k_prep<<<512, 256, 0, stream>>>(W_ih, W_hh, b_ih, b_hh, enc, embt, Wa, captions,
                                  wih_hi, wih_lo, whh_hi, whh_lo, enc_bf, emb_bf,
                                  bias_arr, score_part, argkey, hb, cb, enc_score,
                                  Fall);
  k_gpre<<<dim3(NBLK, 21), 256, 0, stream>>>(wih_hi, wih_lo, enc_bf, emb_bf,
                                             Genc, Gemb);

  for (int t = 0; t < T_; ++t) {
    k_step<<<NBLK + NCONV, 512, 0, stream>>>(
        enc, embt, Wa, ba, W_ih, W_hh, b_ih, b_hh,
        Wl, bl, captions, tf, Genc, Gemb,
        whh_hi, whh_lo, bias_arr, enc_score,
        score_part, Fall, hb, cb, argkey, wl_bf, t);
  }
  k_gemm<<<V_ / GM, 512, 2 * BUFB, stream>>>(wl_bf, Fall, bl, out);
  k_lsm<<<B_ * T_, 256, 0, stream>>>(out);
}

// Round 20
// 670.627 us; speedup vs baseline: 1.3820x; 1.0790x over previous
//
#include <hip/hip_runtime.h>
#include <hip/hip_bf16.h>
#include <stdint.h>

#define B_   32
#define K_   64
#define E_   512
#define H_   512
#define M_   512
#define T_   20
#define V_   32000
#define KIN  2048   // 2H + E + M
#define NBLK 32     // chain blocks / j-groups
#define NCONV 224   // conv helper blocks in k_step

typedef __bf16 bf16x8 __attribute__((ext_vector_type(8)));
typedef float  f32x4  __attribute__((ext_vector_type(4)));

__device__ inline unsigned short f2bf_rne(float f) {
  union { float f; unsigned u; } v; v.f = f;
  unsigned r = v.u + 0x7FFFu + ((v.u >> 16) & 1u);
  return (unsigned short)(r >> 16);
}
__device__ inline float bf2f(unsigned short s) {
  union { unsigned u; float f; } v; v.u = ((unsigned)s) << 16;
  return v.f;
}
__device__ inline float sigm(float x) { return 1.f / (1.f + expf(-x)); }
__device__ inline unsigned ordf(float f) {
  unsigned u = __float_as_uint(f);
  return (u & 0x80000000u) ? ~u : (u | 0x80000000u);
}
__device__ __forceinline__ void gload16(const void* g, void* l) {
  __builtin_amdgcn_global_load_lds(
      (const __attribute__((address_space(1))) void*)g,
      (__attribute__((address_space(3))) void*)l, 16, 0, 0);
}

// j-group mapping: block blk owns jj in [0,64): global j = (jj>>4)*512 + blk*16 + (jj&15)

// ---- prep (+init merged): weight splits, enc/emb bf16, F emb cols, bias,
//      zeros, h0/c0, F[0] h/c, enc_score, score_part[0] --------------------
__global__ void k_prep(const float* __restrict__ W_ih, const float* __restrict__ W_hh,
                       const float* __restrict__ b_ih, const float* __restrict__ b_hh,
                       const float* __restrict__ enc, const float* __restrict__ embt,
                       const float* __restrict__ Wa, const int* __restrict__ captions,
                       unsigned short* __restrict__ wih_hi, unsigned short* __restrict__ wih_lo,
                       unsigned short* __restrict__ whh_hi, unsigned short* __restrict__ whh_lo,
                       unsigned short* __restrict__ enc_bf, unsigned short* __restrict__ emb_bf,
                       float* __restrict__ bias_arr, float* __restrict__ score_part,
                       unsigned long long* __restrict__ argkey,
                       float* __restrict__ hb, float* __restrict__ cb,
                       float* __restrict__ enc_score,
                       unsigned short* __restrict__ Fall) {
  int tid0 = blockIdx.x * 256 + threadIdx.x;
  int NT = gridDim.x * 256;
  for (int i = tid0; i < 2048 * 1024; i += NT) {            // W_ih hi/lo
    float f = W_ih[i];
    unsigned short h = f2bf_rne(f);
    wih_hi[i] = h; wih_lo[i] = f2bf_rne(f - bf2f(h));
  }
  for (int i = tid0; i < NBLK * 64 * 512; i += NT) {        // W_hh rearranged [blk][jj][512]
    int e = i & 511, jj = (i >> 9) & 63, blk = i >> 15;
    int jg = (jj >> 4) * 512 + blk * 16 + (jj & 15);
    float f = W_hh[jg * 512 + e];
    unsigned short h = f2bf_rne(f);
    whh_hi[i] = h; whh_lo[i] = f2bf_rne(f - bf2f(h));
  }
  for (int i = tid0; i < 2048 * 512; i += NT) enc_bf[i] = f2bf_rne(enc[i]);
  for (int i = tid0; i < 640 * 512; i += NT) {              // emb rows + F emb cols (tf=1)
    int n = i >> 9, m = i & 511;
    int t = n >> 5, b = n & 31;
    int tok = captions[b * T_ + (t > 0 ? t - 1 : 0)];
    unsigned short ev = f2bf_rne(embt[(size_t)tok * 512 + m]);
    emb_bf[i] = ev;
    Fall[(size_t)n * KIN + 1536 + m] = ev;
  }
  for (int i = tid0; i < 2048; i += NT) {                   // bias [blk][jj]
    int blk = i >> 6, jj = i & 63;
    int jg = (jj >> 4) * 512 + blk * 16 + (jj & 15);
    bias_arr[i] = b_ih[jg] + b_hh[jg];
  }
  for (int i = tid0; i < (T_ + 1) * 1024; i += NT)
    if (i >= 32) score_part[i] = 0.f;                       // init owns [0,32)
  for (int i = tid0; i < 32; i += NT) argkey[i] = 0ull;

  // ---- merged k_init (blocks 0..63; same idx mapping as before) ----------
  if (blockIdx.x < 64) {
    int idx = blockIdx.x * 256 + threadIdx.x;
    int b = idx >> 9, i = idx & 511;
    float v = enc[(size_t)b * K_ * E_ + (size_t)(K_ - 1) * E_ + i];
    hb[b * H_ + i] = v;
    cb[b * H_ + i] = v;
    unsigned short bv = f2bf_rne(v);
    Fall[b * KIN + i] = bv;
    Fall[b * KIN + H_ + i] = bv;
    if (idx < B_ * K_) {
      int bb = idx >> 6, k = idx & 63;
      const float4* e4  = (const float4*)(enc + ((size_t)bb * K_ + k) * E_);
      const float4* wa4 = (const float4*)(Wa + 2 * H_);
      float acc = 0.f;
      #pragma unroll 4
      for (int q = 0; q < E_ / 4; ++q) {
        float4 a = e4[q], w = wa4[q];
        acc += a.x * w.x + a.y * w.y + a.z * w.z + a.w * w.w;
      }
      enc_score[idx] = acc;
    }
    if (idx < 2048) {   // score_part[0][0][b] = dot([h0,c0], Wa[:1024]), h0=c0
      int bb = idx >> 6, l = idx & 63;
      float s = 0.f;
      #pragma unroll
      for (int q = 0; q < 8; ++q) {
        int ii = l * 8 + q;
        float hv = enc[(size_t)bb * K_ * E_ + (size_t)(K_ - 1) * E_ + ii];
        s += hv * (Wa[ii] + Wa[512 + ii]);
      }
      for (int o = 32; o; o >>= 1) s += __shfl_down(s, o);
      if (l == 0) score_part[bb] = s;
    }
  }
}

// ---- precompute G = (W_ih hi/lo) @ B^T -> bf16, enc+emb via blockIdx.y ---
__global__ __launch_bounds__(256) void k_gpre(
    const unsigned short* __restrict__ whi, const unsigned short* __restrict__ wlo,
    const unsigned short* __restrict__ enc_bf, const unsigned short* __restrict__ emb_bf,
    unsigned short* __restrict__ Genc, unsigned short* __restrict__ Gemb) {
  int blk = blockIdx.x;
  int nt = blockIdx.y;
  const unsigned short* Bm;
  unsigned short* outp;
  int N, koff;
  if (nt < 16) { Bm = enc_bf; outp = Genc; N = 2048; koff = 0; }
  else         { Bm = emb_bf; outp = Gemb; N = 640;  koff = 512; nt -= 16; }
  int tid = threadIdx.x;
  int l = tid & 63, w = tid >> 6, lv = l & 15, lg = l >> 4;
  const int n0 = nt * 128 + w * 32;

  f32x4 acc[4][2];
  #pragma unroll
  for (int jf = 0; jf < 4; ++jf)
    #pragma unroll
    for (int nf = 0; nf < 2; ++nf) acc[jf][nf] = (f32x4){0.f, 0.f, 0.f, 0.f};

  #pragma unroll 4
  for (int kk = 0; kk < 16; ++kk) {
    bf16x8 bfr[2];
    #pragma unroll
    for (int nf = 0; nf < 2; ++nf)
      bfr[nf] = *(const bf16x8*)(Bm + (size_t)(n0 + nf * 16 + lv) * 512 + kk * 32 + lg * 8);
    #pragma unroll
    for (int jf = 0; jf < 4; ++jf) {
      int jg = jf * 512 + blk * 16 + lv;
      bf16x8 ahi = *(const bf16x8*)(whi + (size_t)jg * 1024 + koff + kk * 32 + lg * 8);
      bf16x8 alo = *(const bf16x8*)(wlo + (size_t)jg * 1024 + koff + kk * 32 + lg * 8);
      #pragma unroll
      for (int nf = 0; nf < 2; ++nf) {
        acc[jf][nf] = __builtin_amdgcn_mfma_f32_16x16x32_bf16(ahi, bfr[nf], acc[jf][nf], 0, 0, 0);
        acc[jf][nf] = __builtin_amdgcn_mfma_f32_16x16x32_bf16(alo, bfr[nf], acc[jf][nf], 0, 0, 0);
      }
    }
  }
  #pragma unroll
  for (int jf = 0; jf < 4; ++jf)
    #pragma unroll
    for (int nf = 0; nf < 2; ++nf)
      #pragma unroll
      for (int jr = 0; jr < 4; ++jr) {
        int n = n0 + nf * 16 + lv;
        int jj = jf * 16 + 4 * lg + jr;
        outp[((size_t)blk * N + n) * 64 + jj] = f2bf_rne(acc[jf][nf][jr]);
      }
}

// ---- per step: blocks 0-31 chain; blocks 32-255 convert Wl slice t -------
__global__ __launch_bounds__(512) void k_step(
    const float* __restrict__ enc, const float* __restrict__ embt,
    const float* __restrict__ Wa, const float* __restrict__ ba,
    const float* __restrict__ W_ih, const float* __restrict__ W_hh,
    const float* __restrict__ b_ih, const float* __restrict__ b_hh,
    const float* __restrict__ Wl, const float* __restrict__ bl,
    const int* __restrict__ captions, const int* __restrict__ tf_flag,
    const unsigned short* __restrict__ Genc, const unsigned short* __restrict__ Gemb,
    const unsigned short* __restrict__ whh_hi, const unsigned short* __restrict__ whh_lo,
    const float* __restrict__ bias_arr, const float* __restrict__ enc_score,
    float* __restrict__ score_part, float* __restrict__ attn_w,
    unsigned short* __restrict__ Fall,
    float* __restrict__ hb, float* __restrict__ cb,
    unsigned long long* __restrict__ argkey, unsigned short* __restrict__ wl_bf,
    int t) {
  const int blk = blockIdx.x;
  const int tid = threadIdx.x;

  if (blk >= NBLK) {
    // ---- convert Wl slice t (1/20 of the matrix) -------------------------
    const int NC = V_ * KIN / 4;              // 16,384,000 f32x4's
    const int per = (NC + T_ - 1) / T_;       // 819,200
    int lo = t * per;
    int hi = lo + per; if (hi > NC) hi = NC;
    for (int i = lo + (blk - NBLK) * 512 + tid; i < hi; i += NCONV * 512) {
      f32x4 v = __builtin_nontemporal_load((const f32x4*)Wl + i);
      ushort4 o;
      o.x = f2bf_rne(v.x); o.y = f2bf_rne(v.y); o.z = f2bf_rne(v.z); o.w = f2bf_rne(v.w);
      ((ushort4*)wl_bf)[i] = o;
    }
    return;
  }

  __shared__ float attn_s[B_ * K_];
  __shared__ float gsA[64 * 33];
  __shared__ float gsH[2][64][32];
  __shared__ float scC[512];
  __shared__ float score_t_[32];
  __shared__ int   token_sp;
  __shared__ float xls[KIN];
  __shared__ float gls[2048];
  __shared__ unsigned long long bred[512];
  const float* cbc = cb + (t & 1) * B_ * H_;
  float* cbn = cb + ((t + 1) & 1) * B_ * H_;

  if (tf_flag[0]) {
    // phase 0: assemble scores (deterministic per-slot partials)
    if (tid < 32) {
      float s = 0.f;
      #pragma unroll 8
      for (int p = 0; p < 32; ++p) s += score_part[t * 1024 + p * 32 + tid];
      score_t_[tid] = s;
    }
    __syncthreads();
    // phase 1: softmax (8 waves x 4 batches; lanes = k); store own attn row
    {
      int w = tid >> 6, l = tid & 63;
      float ba0 = ba[0];
      #pragma unroll
      for (int bb = 0; bb < 4; ++bb) {
        int b = w * 4 + bb;
        float s = tanhf(score_t_[b] + enc_score[b * 64 + l] + ba0);
        float m = s;
        for (int o = 32; o; o >>= 1) m = fmaxf(m, __shfl_xor(m, o));
        float e = expf(s - m);
        float sum = e;
        for (int o = 32; o; o >>= 1) sum += __shfl_xor(sum, o);
        float a = e / sum;
        attn_s[b * 64 + l] = a;
        if (b == blk) attn_w[(t * 32 + b) * 64 + l] = a;   // for deferred k_fill
      }
    }
    __syncthreads();
    // phase 2: gsA[jj][b] = sum_k attn*Genc + Gemb + bias (Genc/Gemb bf16)
    {
      int b = tid >> 4, jj4 = tid & 15;
      const unsigned short* gp = Genc + ((size_t)blk * 2048 + b * 64) * 64 + jj4 * 4;
      const float* ap = attn_s + b * 64;
      f32x4 s = {0.f, 0.f, 0.f, 0.f};
      #pragma unroll 8
      for (int k = 0; k < 64; ++k) {
        float a = ap[k];
        ushort4 g = *(const ushort4*)(gp + (size_t)k * 64);
        s[0] += a * bf2f(g.x); s[1] += a * bf2f(g.y);
        s[2] += a * bf2f(g.z); s[3] += a * bf2f(g.w);
      }
      ushort4 e = *(const ushort4*)(Gemb + ((size_t)blk * 640 + t * 32 + b) * 64 + jj4 * 4);
      const f32x4* B4 = (const f32x4*)bias_arr;
      f32x4 bb = B4[blk * 16 + jj4];
      float ef[4] = {bf2f(e.x), bf2f(e.y), bf2f(e.z), bf2f(e.w)};
      #pragma unroll
      for (int q = 0; q < 4; ++q) {
        float v = s[q] + (ef[q] + bb[q]);
        gsA[(jj4 * 4 + q) * 33 + b] = v;
      }
    }
    // phase 3: (W_hh hi/lo) @ h_t, K split across wave pairs (r5 pattern)
    {
      int w = tid >> 6, l = tid & 63, lv = l & 15, lg = l >> 4;
      int g = w & 3, h2 = w >> 2;
      const unsigned short* ah = whh_hi + ((size_t)blk * 64 + g * 16 + lv) * 512 + h2 * 256 + lg * 8;
      const unsigned short* al = whh_lo + ((size_t)blk * 64 + g * 16 + lv) * 512 + h2 * 256 + lg * 8;
      const unsigned short* f0 = Fall + ((size_t)t * 32 + lv) * KIN + h2 * 256 + lg * 8;
      const unsigned short* f1 = Fall + ((size_t)t * 32 + 16 + lv) * KIN + h2 * 256 + lg * 8;
      f32x4 a0 = {0.f, 0.f, 0.f, 0.f};
      f32x4 a1 = {0.f, 0.f, 0.f, 0.f};
      #pragma unroll 8
      for (int kk = 0; kk < 8; ++kk) {
        bf16x8 hi = *(const bf16x8*)(ah + kk * 32);
        bf16x8 lo = *(const bf16x8*)(al + kk * 32);
        bf16x8 b0 = *(const bf16x8*)(f0 + kk * 32);
        bf16x8 b1 = *(const bf16x8*)(f1 + kk * 32);
        a0 = __builtin_amdgcn_mfma_f32_16x16x32_bf16(hi, b0, a0, 0, 0, 0);
        a0 = __builtin_amdgcn_mfma_f32_16x16x32_bf16(lo, b0, a0, 0, 0, 0);
        a1 = __builtin_amdgcn_mfma_f32_16x16x32_bf16(hi, b1, a1, 0, 0, 0);
        a1 = __builtin_amdgcn_mfma_f32_16x16x32_bf16(lo, b1, a1, 0, 0, 0);
      }
      #pragma unroll
      for (int jr = 0; jr < 4; ++jr) {
        int jj = g * 16 + 4 * lg + jr;
        gsH[h2][jj][lv]      = a0[jr];
        gsH[h2][jj][16 + lv] = a1[jr];
      }
    }
    __syncthreads();
    // phase 4: pointwise LSTM + F[t+1] h/c + score partials (one out/thread)
    {
      int b = tid & 31, r = tid >> 5;
      int ii = blk * 16 + r;
      float ig = gsA[(r) * 33 + b]      + gsH[0][r][b]      + gsH[1][r][b];
      float fg = gsA[(16 + r) * 33 + b] + gsH[0][16 + r][b] + gsH[1][16 + r][b];
      float gg = gsA[(32 + r) * 33 + b] + gsH[0][32 + r][b] + gsH[1][32 + r][b];
      float og = gsA[(48 + r) * 33 + b] + gsH[0][48 + r][b] + gsH[1][48 + r][b];
      float cv = cbc[b * H_ + ii];
      float cn = sigm(fg) * cv + sigm(ig) * tanhf(gg);
      float hn = sigm(og) * tanhf(cn);
      cbn[b * H_ + ii] = cn;
      Fall[((size_t)(t + 1) * 32 + b) * KIN + ii] = f2bf_rne(hn);
      Fall[((size_t)(t + 1) * 32 + b) * KIN + H_ + ii] = f2bf_rne(cn);
      scC[r * 32 + b] = hn * Wa[ii] + cn * Wa[512 + ii];
    }
    __syncthreads();
    if (tid < 32) {
      float s = 0.f;
      #pragma unroll
      for (int r = 0; r < 16; ++r) s += scC[r * 32 + tid];
      score_part[(t + 1) * 1024 + blk * 32 + tid] = s;
    }
  } else {
    // ---------- tf==0 slow correctness path: block owns batch b = blk ----
    const int b = blk;
    const float* hbc = hb + (t & 1) * B_ * H_;
    float* hbn = hb + ((t + 1) & 1) * B_ * H_;
    if (tid == 0) {
      float s = 0.f;
      for (int p = 0; p < 32; ++p) s += score_part[t * 1024 + p * 32 + b];
      score_t_[0] = s;
      token_sp = (t == 0) ? captions[b * T_]
                          : (int)(0xFFFFFFFFu - (unsigned)(argkey[b] & 0xFFFFFFFFull));
    }
    __syncthreads();
    if (tid < 64) {
      float s = tanhf(score_t_[0] + enc_score[b * 64 + tid] + ba[0]);
      float m = s;
      for (int o = 32; o; o >>= 1) m = fmaxf(m, __shfl_xor(m, o));
      float e = expf(s - m);
      float sum = e;
      for (int o = 32; o; o >>= 1) sum += __shfl_xor(sum, o);
      attn_s[tid] = e / sum;
    }
    __syncthreads();
    for (int i = tid; i < 512; i += 512) {
      xls[i] = hbc[b * H_ + i];
      xls[512 + i] = cbc[b * H_ + i];
      float a = 0.f;
      for (int k = 0; k < 64; ++k) a += attn_s[k] * enc[((size_t)b * 64 + k) * 512 + i];
      xls[1024 + i] = a;
      xls[1536 + i] = embt[(size_t)token_sp * 512 + i];
    }
    __syncthreads();
    for (int i = tid; i < 1024; i += 512)
      Fall[((size_t)t * 32 + b) * KIN + 1024 + i] = f2bf_rne(xls[1024 + i]);
    for (int j = tid; j < 2048; j += 512) {
      float a = b_ih[j] + b_hh[j];
      for (int e = 0; e < 1024; ++e) a += W_ih[(size_t)j * 1024 + e] * xls[1024 + e];
      for (int e = 0; e < 512; ++e)  a += W_hh[(size_t)j * 512 + e] * xls[e];
      gls[j] = a;
    }
    __syncthreads();
    {
      float sc = 0.f;
      for (int i = tid; i < 512; i += 512) {
        float ig = gls[i], fg = gls[512 + i], gg = gls[1024 + i], og = gls[1536 + i];
        float cv = xls[512 + i];
        float cn = sigm(fg) * cv + sigm(ig) * tanhf(gg);
        float hn = sigm(og) * tanhf(cn);
        hbn[b * H_ + i] = hn;
        cbn[b * H_ + i] = cn;
        Fall[((size_t)(t + 1) * 32 + b) * KIN + i] = f2bf_rne(hn);
        Fall[((size_t)(t + 1) * 32 + b) * KIN + H_ + i] = f2bf_rne(cn);
        sc += hn * Wa[i] + cn * Wa[512 + i];
      }
      scC[tid] = sc;
    }
    __syncthreads();
    if (tid == 0) {
      float s = 0.f;
      for (int q = 0; q < 512; ++q) s += scC[q];
      score_part[(t + 1) * 1024 + b] = s;
    }
    unsigned long long best = 0ull;
    for (int v = tid; v < V_; v += 512) {
      float d = bl[v];
      const float* wr = Wl + (size_t)v * KIN;
      for (int k = 0; k < KIN; ++k) d += wr[k] * xls[k];
      unsigned long long key = ((unsigned long long)ordf(d) << 32) | (0xFFFFFFFFu - (unsigned)v);
      if (key > best) best = key;
    }
    bred[tid] = best;
    __syncthreads();
    for (int o = 256; o; o >>= 1) {
      if (tid < o) bred[tid] = bred[tid] > bred[tid + o] ? bred[tid] : bred[tid + o];
      __syncthreads();
    }
    if (tid == 0) argkey[b] = bred[0];
  }
}

// ---- deferred context fill from stored attn weights (tf==1; r11 proven) --
__global__ void k_fill(const float* __restrict__ enc,
                       const float* __restrict__ attn_w, const int* __restrict__ tf_flag,
                       unsigned short* __restrict__ Fall) {
  if (tf_flag[0] == 0) return;
  int n = blockIdx.x;           // 640 = (t,b)
  int b = n & 31;
  int tid = threadIdx.x;
  __shared__ float aw[64];
  if (tid < 64) aw[tid] = attn_w[n * 64 + tid];
  __syncthreads();
  for (int e = tid; e < 512; e += 256) {
    float a = 0.f;
    #pragma unroll 8
    for (int k = 0; k < 64; ++k) a += aw[k] * enc[((size_t)b * 64 + k) * 512 + e];
    Fall[(size_t)n * KIN + 1024 + e] = f2bf_rne(a);
  }
}

// ---- batched logits GEMM (proven v2, FROZEN): C[v][n] = Wl[v]·F[n] -------
#define GM   128
#define GNP  320
#define ABYTES 40960
#define BUFB  57344

__global__ __launch_bounds__(512, 2) void k_gemm(
    const unsigned short* __restrict__ wl_bf,
    const unsigned short* __restrict__ F,
    const float* __restrict__ bl,
    float* __restrict__ out) {
  extern __shared__ unsigned char lds[];
  const int tid = threadIdx.x;
  const int l = tid & 63, w = tid >> 6, lv = l & 15, lg = l >> 4;
  const int wm = w >> 2, wn = w & 3;
  const int m0 = blockIdx.x * GM;

  float blv[4];
  #pragma unroll
  for (int mi = 0; mi < 4; ++mi) blv[mi] = bl[m0 + wm * 64 + mi * 16 + lv];

  f32x4 acc[4][5];
  #pragma unroll
  for (int mi = 0; mi < 4; ++mi)
    #pragma unroll
    for (int ni = 0; ni < 5; ++ni) acc[mi][ni] = (f32x4){0.f, 0.f, 0.f, 0.f};

#define STAGE(c, buf) do {                                                    \
    int kb_ = ((c) & 31) * 64;                                                \
    int nb_ = ((c) >> 5) * GNP;                                               \
    unsigned char* bs_ = lds + (buf) * BUFB;                                  \
    _Pragma("unroll")                                                         \
    for (int i_ = 0; i_ < 5; ++i_) {                                          \
      int s_ = i_ * 512 + tid;                                                \
      int kq_ = s_ / 320, n_ = s_ - kq_ * 320;                                \
      gload16(F + (size_t)(nb_ + n_) * KIN + kb_ + kq_ * 8, bs_ + s_ * 16);   \
    }                                                                         \
    _Pragma("unroll")                                                         \
    for (int j_ = 0; j_ < 2; ++j_) {                                          \
      int s_ = j_ * 512 + tid;                                                \
      int kq_ = s_ >> 7, m_ = s_ & 127;                                       \
      gload16(wl_bf + (size_t)(m0 + m_) * KIN + kb_ + kq_ * 8,                \
              bs_ + ABYTES + s_ * 16);                                        \
    }                                                                         \
  } while (0)

#define COMPUTE(buf) do {                                                     \
    unsigned char* bs_ = lds + (buf) * BUFB;                                  \
    _Pragma("unroll")                                                         \
    for (int kk2_ = 0; kk2_ < 2; ++kk2_) {                                    \
      int kq_ = kk2_ * 4 + lg;                                                \
      bf16x8 bf_[4];                                                          \
      _Pragma("unroll")                                                       \
      for (int mi = 0; mi < 4; ++mi)                                          \
        bf_[mi] = *(const bf16x8*)(bs_ + ABYTES +                             \
                    (size_t)(kq_ * 128 + wm * 64 + mi * 16 + lv) * 16);       \
      _Pragma("unroll")                                                       \
      for (int ni = 0; ni < 5; ++ni) {                                        \
        bf16x8 af_ = *(const bf16x8*)(bs_ +                                   \
                    (size_t)(kq_ * 320 + wn * 80 + ni * 16 + lv) * 16);       \
        _Pragma("unroll")                                                     \
        for (int mi = 0; mi < 4; ++mi)                                        \
          acc[mi][ni] = __builtin_amdgcn_mfma_f32_16x16x32_bf16(              \
                          af_, bf_[mi], acc[mi][ni], 0, 0, 0);                \
      }                                                                       \
    }                                                                         \
  } while (0)

#define WRITEOUT(pass) do {                                                   \
    _Pragma("unroll")                                                         \
    for (int mi = 0; mi < 4; ++mi) {                                          \
      int v_ = m0 + wm * 64 + mi * 16 + lv;                                   \
      _Pragma("unroll")                                                       \
      for (int ni = 0; ni < 5; ++ni) {                                        \
        _Pragma("unroll")                                                     \
        for (int j_ = 0; j_ < 4; ++j_) {                                      \
          int n_ = (pass) * GNP + wn * 80 + ni * 16 + 4 * lg + j_;            \
          int tt_ = n_ >> 5, bb_ = n_ & 31;                                   \
          out[((size_t)bb_ * T_ + tt_) * V_ + v_] = acc[mi][ni][j_] + blv[mi];\
        }                                                                     \
      }                                                                       \
    }                                                                         \
  } while (0)

  STAGE(0, 0);
  int cur = 0;
  for (int c = 0; c < 64; ++c) {
    __syncthreads();
    if (c < 63) STAGE(c + 1, cur ^ 1);
    COMPUTE(cur);
    if (c == 31) {
      WRITEOUT(0);
      #pragma unroll
      for (int mi = 0; mi < 4; ++mi)
        #pragma unroll
        for (int ni = 0; ni < 5; ++ni) acc[mi][ni] = (f32x4){0.f, 0.f, 0.f, 0.f};
    }
    cur ^= 1;
  }
  WRITEOUT(1);
#undef STAGE
#undef COMPUTE
#undef WRITEOUT
}

// ---- final: in-place log_softmax -----------------------------------------
__global__ void k_lsm(float* __restrict__ out) {
  float4* p = (float4*)(out + (size_t)blockIdx.x * V_);
  int tid = threadIdx.x;
  __shared__ float smax[4], ssum[4];
  const int N4 = V_ / 4;
  float m = -1e30f, s = 0.f;
  for (int i = tid; i < N4; i += 256) {
    float4 v = p[i];
    float lm = fmaxf(fmaxf(v.x, v.y), fmaxf(v.z, v.w));
    if (lm > m) { s *= expf(m - lm); m = lm; }
    s += expf(v.x - m) + expf(v.y - m) + expf(v.z - m) + expf(v.w - m);
  }
  for (int o = 32; o; o >>= 1) {
    float m2 = __shfl_xor(m, o), s2 = __shfl_xor(s, o);
    float mn = fmaxf(m, m2);
    s = s * expf(m - mn) + s2 * expf(m2 - mn);
    m = mn;
  }
  if ((tid & 63) == 0) { smax[tid >> 6] = m; ssum[tid >> 6] = s; }
  __syncthreads();
  float mg = fmaxf(fmaxf(smax[0], smax[1]), fmaxf(smax[2], smax[3]));
  float sg = ssum[0] * expf(smax[0] - mg) + ssum[1] * expf(smax[1] - mg)
           + ssum[2] * expf(smax[2] - mg) + ssum[3] * expf(smax[3] - mg);
  float lse = mg + logf(sg);
  for (int i = tid; i < N4; i += 256) {
    float4 v = p[i];
    v.x -= lse; v.y -= lse; v.z -= lse; v.w -= lse;
    p[i] = v;
  }
}

extern "C" void kernel_launch(void* const* d_in, const int* in_sizes, int n_in,
                              void* d_out, int out_size, void* d_ws, size_t ws_size,
                              hipStream_t stream) {
  const float* enc      = (const float*)d_in[0];
  const float* embt     = (const float*)d_in[1];
  const float* Wa       = (const float*)d_in[2];
  const float* ba       = (const float*)d_in[3];
  const float* W_ih     = (const float*)d_in[4];
  const float* W_hh     = (const float*)d_in[5];
  const float* b_ih     = (const float*)d_in[6];
  const float* b_hh     = (const float*)d_in[7];
  const float* Wl       = (const float*)d_in[8];
  const float* bl       = (const float*)d_in[9];
  const int*   captions = (const int*)d_in[10];
  const int*   tf       = (const int*)d_in[11];
  float* out = (float*)d_out;
  char*  ws  = (char*)d_ws;

  size_t off = 0;
  unsigned short* Fall = (unsigned short*)(ws + off); off += (size_t)(T_ + 1) * B_ * KIN * 2;
  float* hb            = (float*)(ws + off);          off += (size_t)2 * B_ * H_ * 4;
  float* cb            = (float*)(ws + off);          off += (size_t)2 * B_ * H_ * 4;
  float* enc_score     = (float*)(ws + off);          off += (size_t)B_ * K_ * 4;
  float* score_part    = (float*)(ws + off);          off += (size_t)(T_ + 1) * 1024 * 4;
  float* attn_w        = (float*)(ws + off);          off += (size_t)T_ * B_ * K_ * 4;
  unsigned long long* argkey = (unsigned long long*)(ws + off); off += 256;
  float* bias_arr      = (float*)(ws + off);          off += 2048 * 4;
  off = (off + 1023) & ~(size_t)1023;
  unsigned short* wih_hi = (unsigned short*)(ws + off); off += (size_t)2048 * 1024 * 2;
  unsigned short* wih_lo = (unsigned short*)(ws + off); off += (size_t)2048 * 1024 * 2;
  unsigned short* whh_hi = (unsigned short*)(ws + off); off += (size_t)NBLK * 64 * 512 * 2;
  unsigned short* whh_lo = (unsigned short*)(ws + off); off += (size_t)NBLK * 64 * 512 * 2;
  unsigned short* enc_bf = (unsigned short*)(ws + off); off += (size_t)2048 * 512 * 2;
  unsigned short* emb_bf = (unsigned short*)(ws + off); off += (size_t)640 * 512 * 2;
  unsigned short* Genc = (unsigned short*)(ws + off); off += (size_t)NBLK * 2048 * 64 * 2;
  unsigned short* Gemb = (unsigned short*)(ws + off); off += (size_t)NBLK * 640 * 64 * 2;
  unsigned short* wl_bf = (unsigned short*)(ws + off); off += (size_t)V_ * KIN * 2;

  k_prep<<<512, 256, 0, stream>>>(W_ih, W_hh, b_ih, b_hh, enc, embt, Wa, captions,
                                  wih_hi, wih_lo, whh_hi, whh_lo, enc_bf, emb_bf,
                                  bias_arr, score_part, argkey, hb, cb, enc_score,
                                  Fall);
  k_gpre<<<dim3(NBLK, 21), 256, 0, stream>>>(wih_hi, wih_lo, enc_bf, emb_bf,
                                             Genc, Gemb);

  for (int t = 0; t < T_; ++t) {
    k_step<<<NBLK + NCONV, 512, 0, stream>>>(
        enc, embt, Wa, ba, W_ih, W_hh, b_ih, b_hh,
        Wl, bl, captions, tf, Genc, Gemb,
        whh_hi, whh_lo, bias_arr, enc_score,
        score_part, attn_w, Fall, hb, cb, argkey, wl_bf, t);
  }
  k_fill<<<T_ * B_, 256, 0, stream>>>(enc, attn_w, tf, Fall);
  k_gemm<<<V_ / GM, 512, 2 * BUFB, stream>>>(wl_bf, Fall, bl, out);
  k_lsm<<<B_ * T_, 256, 0, stream>>>(out);
}